// Round 1
// baseline (1849.311 us; speedup 1.0000x reference)
//
#include <hip/hip_runtime.h>
#include <math.h>

#define B_ 4
#define N_ 20000
#define E_ 100000
#define C_ 128
#define K_ 32
#define ABLK 64      // stage-A blocks per batch
#define NPB_A 313    // nodes per stage-A block (64*313 >= 20000)

__device__ __forceinline__ float gelu_exact(float x){
    return 0.5f * x * (1.0f + erff(x * 0.70710678118654752f));
}

// ---------------- setup kernels ----------------

__global__ __launch_bounds__(256) void basis_kernel(
    const float* __restrict__ nodes, const float* __restrict__ nw,
    const float* __restrict__ modes, const float* __restrict__ latent,
    float* __restrict__ bc, float* __restrict__ bs, float* __restrict__ wts)
{
    int idx = blockIdx.x*256 + threadIdx.x;
    if (idx >= B_*N_) return;
    float iL0 = 0.5f + 1.5f/(1.f+expf(-latent[0]));
    float iL1 = 0.5f + 1.5f/(1.f+expf(-latent[1]));
    float iL2 = 0.5f + 1.5f/(1.f+expf(-latent[2]));
    float p0 = nodes[(size_t)idx*3+0]*iL0;
    float p1 = nodes[(size_t)idx*3+1]*iL1;
    float p2 = nodes[(size_t)idx*3+2]*iL2;
    #pragma unroll
    for (int k=0;k<K_;k++){
        float t = p0*modes[k*3+0] + p1*modes[k*3+1] + p2*modes[k*3+2];
        bc[(size_t)idx*K_+k] = cosf(t);
        bs[(size_t)idx*K_+k] = sinf(t);
    }
    wts[idx] = nw[idx];
}

__global__ __launch_bounds__(256) void fc0_kernel(
    const float* __restrict__ x, const float* __restrict__ w,
    const float* __restrict__ bvec, float* __restrict__ h)
{
    int idx = blockIdx.x*256 + threadIdx.x;
    if (idx >= B_*N_) return;
    float x0 = x[(size_t)idx*3+0], x1 = x[(size_t)idx*3+1], x2 = x[(size_t)idx*3+2];
    float* hr = h + (size_t)idx*C_;
    for (int c=0;c<C_;c+=4){
        float4 v;
        v.x = bvec[c+0] + x0*w[(c+0)*3] + x1*w[(c+0)*3+1] + x2*w[(c+0)*3+2];
        v.y = bvec[c+1] + x0*w[(c+1)*3] + x1*w[(c+1)*3+1] + x2*w[(c+1)*3+2];
        v.z = bvec[c+2] + x0*w[(c+2)*3] + x1*w[(c+2)*3+1] + x2*w[(c+2)*3+2];
        v.w = bvec[c+3] + x0*w[(c+3)*3] + x1*w[(c+3)*3+1] + x2*w[(c+3)*3+2];
        *(float4*)(hr+c) = v;
    }
}

// ---------------- CSR build ----------------

__global__ __launch_bounds__(256) void hist_kernel(
    const int* __restrict__ edges, int* __restrict__ cnt)
{
    int idx = blockIdx.x*256 + threadIdx.x;
    if (idx >= B_*E_) return;
    int b = idx / E_;
    int t = edges[(size_t)idx*2];
    atomicAdd(cnt + b*N_ + t, 1);
}

__global__ __launch_bounds__(256) void scan_kernel(
    const int* __restrict__ cnt, int* __restrict__ rowptr, int* __restrict__ cur)
{
    __shared__ int sd[256];
    int b = blockIdx.x, tid = threadIdx.x;
    int run = 0;
    for (int base=0; base<N_; base+=256){
        int n = base + tid;
        int v = (n<N_) ? cnt[b*N_+n] : 0;
        sd[tid] = v; __syncthreads();
        #pragma unroll
        for (int off=1; off<256; off<<=1){
            int t = (tid>=off) ? sd[tid-off] : 0;
            __syncthreads();
            sd[tid] += t;
            __syncthreads();
        }
        if (n<N_){
            int excl = run + sd[tid] - v;
            rowptr[b*(N_+1)+n] = excl;
            cur[b*N_+n] = excl;
        }
        run += sd[255];
        __syncthreads();
    }
    if (tid==0) rowptr[b*(N_+1)+N_] = run;
}

__global__ __launch_bounds__(256) void fill_kernel(
    const int* __restrict__ edges, int* __restrict__ cur, int* __restrict__ csre)
{
    int idx = blockIdx.x*256 + threadIdx.x;
    if (idx >= B_*E_) return;
    int b = idx / E_, e = idx - b*E_;
    int t = edges[(size_t)idx*2];
    int pos = atomicAdd(cur + b*N_ + t, 1);
    csre[(size_t)b*E_ + pos] = e;
}

// ---------------- per-layer: spectral reduce (stage A) ----------------
// xc[b,c,k] = sum_n (h[b,n,c]*w[b,n]) * bc[b,n,k]; xs likewise with bs; x0 = sum_n h*w.
// Block = (batch, node-range). 256 threads = 128 c x 2 k-halves; partials to global.

__global__ __launch_bounds__(256) void stageA_kernel(
    const float* __restrict__ h, const float* __restrict__ bc,
    const float* __restrict__ bs, const float* __restrict__ wts,
    float* __restrict__ part)
{
    __shared__ float lbc[32*K_], lbs[32*K_], lw[32];
    int b = blockIdx.y, blk = blockIdx.x;
    int n0base = blk*NPB_A;
    int nEnd = min(N_, n0base + NPB_A);
    int tid = threadIdx.x;
    int c = tid & 127, half = tid >> 7, kOff = half*16;
    float aC[16], aS[16], a0 = 0.f;
    #pragma unroll
    for (int kk=0;kk<16;kk++){ aC[kk]=0.f; aS[kk]=0.f; }
    size_t bN = (size_t)b*N_;
    for (int n0 = n0base; n0 < nEnd; n0 += 32){
        for (int j = tid; j < 32*K_; j += 256){
            int node = n0 + (j>>5); int kk = j & 31;
            float vc=0.f, vs=0.f;
            if (node < nEnd){ vc = bc[(bN+node)*K_+kk]; vs = bs[(bN+node)*K_+kk]; }
            lbc[j]=vc; lbs[j]=vs;
        }
        if (tid < 32){ int node = n0+tid; lw[tid] = (node<nEnd) ? wts[bN+node] : 0.f; }
        __syncthreads();
        int jmax = min(32, nEnd - n0);
        for (int j=0;j<jmax;j++){
            float hw = h[(bN + n0 + j)*C_ + c] * lw[j];
            #pragma unroll
            for (int kk=0;kk<16;kk++){
                aC[kk] += hw * lbc[j*K_+kOff+kk];
                aS[kk] += hw * lbs[j*K_+kOff+kk];
            }
            a0 += hw;
        }
        __syncthreads();
    }
    size_t base = (((size_t)b*ABLK + blk)*C_ + c)*65;
    #pragma unroll
    for (int kk=0;kk<16;kk++){
        part[base + kOff + kk]      = aC[kk];
        part[base + 32 + kOff + kk] = aS[kk];
    }
    if (half==0) part[base+64] = a0;
}

__global__ __launch_bounds__(256) void reducePart_kernel(
    const float* __restrict__ part, float* __restrict__ xq)
{
    int idx = blockIdx.x*256 + threadIdx.x;
    if (idx >= B_*C_*65) return;
    int b = idx / (C_*65);
    int r = idx - b*C_*65;
    float s = 0.f;
    for (int blk=0; blk<ABLK; blk++)
        s += part[((size_t)(b*ABLK+blk))*C_*65 + r];
    xq[idx] = s;
}

// ---------------- per-layer: mode mixing (tiny) ----------------
// wf[b,o,0:32]=2*fc, wf[b,o,32:64]=-2*fs ; f0[b,o]

__global__ __launch_bounds__(64) void mix_kernel(
    const float* __restrict__ xq, const float* __restrict__ swc_l,
    const float* __restrict__ sws_l, const float* __restrict__ sw0_l,
    float* __restrict__ wf, float* __restrict__ f0)
{
    __shared__ float s64[64];
    int o = blockIdx.x, b = blockIdx.y, t = threadIdx.x;
    int k = t & 31; bool isS = t >= 32;
    const float* xqb = xq + (size_t)b*C_*65;
    float acc = 0.f;
    for (int c=0;c<C_;c++){
        float xc = xqb[c*65 + k], xs = xqb[c*65 + 32 + k];
        float wc = swc_l[((size_t)c*C_+o)*K_ + k];
        float ws = sws_l[((size_t)c*C_+o)*K_ + k];
        acc += isS ? (xs*wc + xc*ws) : (xc*wc - xs*ws);
    }
    wf[((size_t)b*C_+o)*64 + t] = isS ? -2.f*acc : 2.f*acc;
    // f0
    float p = xqb[t*65+64]      * sw0_l[(size_t)t*C_+o]
            + xqb[(t+64)*65+64] * sw0_l[(size_t)(t+64)*C_+o];
    s64[t] = p; __syncthreads();
    if (t==0){
        float s=0.f;
        for (int i=0;i<64;i++) s += s64[i];
        f0[b*C_+o] = s;
    }
}

// ---------------- per-layer: gradient gather (CSR) ----------------
// g[b,n,c*3+d] = sum_{e: tgt=n} egw[b,e,d]*(h[b,src,c]-h[b,n,c])

__global__ __launch_bounds__(256) void grad_kernel(
    const float* __restrict__ h, const int* __restrict__ edges,
    const float* __restrict__ egw, const int* __restrict__ rowptr,
    const int* __restrict__ csre, float* __restrict__ g)
{
    int b = blockIdx.y;
    int n = blockIdx.x*2 + (threadIdx.x >> 7);
    int c = threadIdx.x & 127;
    size_t bN = (size_t)b*N_;
    int r0 = rowptr[b*(N_+1)+n], r1 = rowptr[b*(N_+1)+n+1];
    float hc = h[(bN+n)*C_ + c];
    float a0=0.f, a1=0.f, a2=0.f;
    for (int i=r0;i<r1;i++){
        int e = csre[(size_t)b*E_ + i];
        size_t eb = (size_t)b*E_ + e;
        int src = edges[eb*2 + 1];
        float w0 = egw[eb*3+0], w1 = egw[eb*3+1], w2 = egw[eb*3+2];
        float d = h[(bN+src)*C_ + c] - hc;
        a0 += w0*d; a1 += w1*d; a2 += w2*d;
    }
    float* gr = g + (bN+n)*(size_t)(C_*3) + c*3;
    gr[0]=a0; gr[1]=a1; gr[2]=a2;
}

// ---------------- per-layer: fused GEMM (K=576) + epilogue ----------------
// out[b,n,o] = sum_k A[b,n,k]*W[b,o,k] + wb[o]+gb[o]+f0[b,o]  (gelu if not last)
// A = [h(128) | g(384) | bc(32) | bs(32)],  W = [ww | gw | wf]

__global__ __launch_bounds__(256) void gemm_kernel(
    const float* __restrict__ h_in, const float* __restrict__ g,
    const float* __restrict__ bc, const float* __restrict__ bs,
    const float* __restrict__ ww_l, const float* __restrict__ wb_l,
    const float* __restrict__ gw_l, const float* __restrict__ gb_l,
    const float* __restrict__ wf, const float* __restrict__ f0,
    float* __restrict__ h_out, int apply_gelu)
{
    __shared__ float As[64*68];    // [k][n], stride 68
    __shared__ float Ws[64*132];   // [k][o], stride 132
    int b = blockIdx.y;
    int nb0 = blockIdx.x*64;
    int tid = threadIdx.x;
    int a_n = tid>>2, a_q = tid&3;
    int w_o = tid>>1, w_h = tid&1;
    int o_base = (tid&31)*4, n_base = (tid>>5)*8;
    float acc[8][4];
    #pragma unroll
    for (int j=0;j<8;j++)
        #pragma unroll
        for (int i=0;i<4;i++) acc[j][i]=0.f;
    size_t bN = (size_t)b*N_;
    int gn = nb0 + a_n; bool av = gn < N_;
    size_t row = bN + (size_t)(av ? gn : 0);
    const float* hrow  = h_in + row*C_;
    const float* grow  = g    + row*(size_t)384;
    const float* bcrow = bc   + row*K_;
    const float* bsrow = bs   + row*K_;
    for (int ch=0; ch<9; ++ch){
        #pragma unroll
        for (int i=0;i<4;i++){
            int kl = a_q*16 + i*4;
            float4 v = make_float4(0.f,0.f,0.f,0.f);
            if (av){
                if (ch<2)      v = *(const float4*)(hrow + ch*64 + kl);
                else if (ch<8) v = *(const float4*)(grow + (ch-2)*64 + kl);
                else           v = (kl<32) ? *(const float4*)(bcrow + kl)
                                           : *(const float4*)(bsrow + kl - 32);
            }
            As[(kl+0)*68 + a_n] = v.x;
            As[(kl+1)*68 + a_n] = v.y;
            As[(kl+2)*68 + a_n] = v.z;
            As[(kl+3)*68 + a_n] = v.w;
        }
        #pragma unroll
        for (int i=0;i<8;i++){
            int kl = w_h*32 + i*4;
            const float* wp;
            if (ch<2)      wp = ww_l + (size_t)w_o*C_  + ch*64 + kl;
            else if (ch<8) wp = gw_l + (size_t)w_o*384 + (ch-2)*64 + kl;
            else           wp = wf   + ((size_t)b*C_ + w_o)*64 + kl;
            float4 v = *(const float4*)wp;
            Ws[(kl+0)*132 + w_o] = v.x;
            Ws[(kl+1)*132 + w_o] = v.y;
            Ws[(kl+2)*132 + w_o] = v.z;
            Ws[(kl+3)*132 + w_o] = v.w;
        }
        __syncthreads();
        #pragma unroll 4
        for (int kk=0;kk<64;kk++){
            float4 wv = *(const float4*)&Ws[kk*132 + o_base];
            float4 a0 = *(const float4*)&As[kk*68 + n_base];
            float4 a1 = *(const float4*)&As[kk*68 + n_base + 4];
            float avj[8] = {a0.x,a0.y,a0.z,a0.w,a1.x,a1.y,a1.z,a1.w};
            float wvi[4] = {wv.x,wv.y,wv.z,wv.w};
            #pragma unroll
            for (int j=0;j<8;j++)
                #pragma unroll
                for (int i=0;i<4;i++)
                    acc[j][i] += avj[j]*wvi[i];
        }
        __syncthreads();
    }
    float bias[4];
    #pragma unroll
    for (int i=0;i<4;i++)
        bias[i] = wb_l[o_base+i] + gb_l[o_base+i] + f0[(size_t)b*C_ + o_base + i];
    #pragma unroll
    for (int j=0;j<8;j++){
        int n = nb0 + n_base + j;
        if (n < N_){
            float4 v;
            v.x = acc[j][0]+bias[0]; v.y = acc[j][1]+bias[1];
            v.z = acc[j][2]+bias[2]; v.w = acc[j][3]+bias[3];
            if (apply_gelu){
                v.x = gelu_exact(v.x); v.y = gelu_exact(v.y);
                v.z = gelu_exact(v.z); v.w = gelu_exact(v.w);
            }
            *(float4*)(h_out + (bN+n)*C_ + o_base) = v;
        }
    }
}

// ---------------- head: fc1 + gelu + fc2 ----------------

__global__ __launch_bounds__(256) void final_kernel(
    const float* __restrict__ h_in,
    const float* __restrict__ fc1w, const float* __restrict__ fc1b,
    const float* __restrict__ fc2w, const float* __restrict__ fc2b,
    float* __restrict__ out)
{
    __shared__ float As[64*68];
    __shared__ float Ws[64*132];   // reused as hidden[n][f] (stride 132)
    __shared__ float p2[256];
    int b = blockIdx.y;
    int nb0 = blockIdx.x*64;
    int tid = threadIdx.x;
    int a_n = tid>>2, a_q = tid&3;
    int w_o = tid>>1, w_h = tid&1;
    int o_base = (tid&31)*4, n_base = (tid>>5)*8;
    float acc[8][4];
    #pragma unroll
    for (int j=0;j<8;j++)
        #pragma unroll
        for (int i=0;i<4;i++) acc[j][i]=0.f;
    size_t bN = (size_t)b*N_;
    int gn = nb0 + a_n; bool av = gn < N_;
    size_t row = bN + (size_t)(av ? gn : 0);
    const float* hrow = h_in + row*C_;
    for (int ch=0; ch<2; ++ch){
        #pragma unroll
        for (int i=0;i<4;i++){
            int kl = a_q*16 + i*4;
            float4 v = make_float4(0.f,0.f,0.f,0.f);
            if (av) v = *(const float4*)(hrow + ch*64 + kl);
            As[(kl+0)*68 + a_n] = v.x;
            As[(kl+1)*68 + a_n] = v.y;
            As[(kl+2)*68 + a_n] = v.z;
            As[(kl+3)*68 + a_n] = v.w;
        }
        #pragma unroll
        for (int i=0;i<8;i++){
            int kl = w_h*32 + i*4;
            const float* wp = fc1w + (size_t)w_o*C_ + ch*64 + kl;
            float4 v = *(const float4*)wp;
            Ws[(kl+0)*132 + w_o] = v.x;
            Ws[(kl+1)*132 + w_o] = v.y;
            Ws[(kl+2)*132 + w_o] = v.z;
            Ws[(kl+3)*132 + w_o] = v.w;
        }
        __syncthreads();
        #pragma unroll 4
        for (int kk=0;kk<64;kk++){
            float4 wv = *(const float4*)&Ws[kk*132 + o_base];
            float4 a0 = *(const float4*)&As[kk*68 + n_base];
            float4 a1 = *(const float4*)&As[kk*68 + n_base + 4];
            float avj[8] = {a0.x,a0.y,a0.z,a0.w,a1.x,a1.y,a1.z,a1.w};
            float wvi[4] = {wv.x,wv.y,wv.z,wv.w};
            #pragma unroll
            for (int j=0;j<8;j++)
                #pragma unroll
                for (int i=0;i<4;i++)
                    acc[j][i] += avj[j]*wvi[i];
        }
        __syncthreads();
    }
    // hidden = gelu(acc + fc1_b) into Ws (safe: all Ws reads done, sync above)
    #pragma unroll
    for (int j=0;j<8;j++){
        int n_l = n_base + j;
        float4 v;
        v.x = gelu_exact(acc[j][0] + fc1b[o_base+0]);
        v.y = gelu_exact(acc[j][1] + fc1b[o_base+1]);
        v.z = gelu_exact(acc[j][2] + fc1b[o_base+2]);
        v.w = gelu_exact(acc[j][3] + fc1b[o_base+3]);
        *(float4*)&Ws[n_l*132 + o_base] = v;
    }
    __syncthreads();
    int n_l = tid & 63, fq = tid >> 6;
    float p = 0.f;
    for (int f = fq*32; f < fq*32+32; f++)
        p += fc2w[f] * Ws[n_l*132 + f];
    p2[tid] = p; __syncthreads();
    if (tid < 64){
        float s = p2[tid] + p2[tid+64] + p2[tid+128] + p2[tid+192] + fc2b[0];
        int n = nb0 + tid;
        if (n < N_) out[bN + n] = s;
    }
}

// ---------------- launch ----------------

extern "C" void kernel_launch(void* const* d_in, const int* in_sizes, int n_in,
                              void* d_out, int out_size, void* d_ws, size_t ws_size,
                              hipStream_t stream)
{
    const float* x      = (const float*)d_in[0];
    // d_in[1] = node_mask (unused by reference)
    const float* nodes  = (const float*)d_in[2];
    const float* nw     = (const float*)d_in[3];
    const int*   edges  = (const int*)  d_in[4];
    const float* egw    = (const float*)d_in[5];
    const float* modes  = (const float*)d_in[6];
    const float* latent = (const float*)d_in[7];
    const float* fc0w   = (const float*)d_in[8];
    const float* fc0b   = (const float*)d_in[9];
    const float* swc    = (const float*)d_in[10];
    const float* sws    = (const float*)d_in[11];
    const float* sw0    = (const float*)d_in[12];
    const float* ww     = (const float*)d_in[13];
    const float* wb     = (const float*)d_in[14];
    const float* gw     = (const float*)d_in[15];
    const float* gb     = (const float*)d_in[16];
    const float* fc1w   = (const float*)d_in[17];
    const float* fc1b   = (const float*)d_in[18];
    const float* fc2w   = (const float*)d_in[19];
    const float* fc2b   = (const float*)d_in[20];
    float* out = (float*)d_out;

    const size_t SZ_BC   = (size_t)B_*N_*K_;      // 2,560,000
    const size_t SZ_W    = (size_t)B_*N_;         // 80,000
    const size_t SZ_H    = (size_t)B_*N_*C_;      // 10,240,000
    const size_t SZ_G    = (size_t)B_*N_*C_*3;    // 30,720,000
    const size_t SZ_PART = (size_t)B_*ABLK*C_*65; // 2,129,920
    const size_t SZ_XQ   = (size_t)B_*C_*65;
    const size_t SZ_WF   = (size_t)B_*C_*64;
    const size_t SZ_F0   = (size_t)B_*C_;

    float* F = (float*)d_ws;
    size_t off = 0;
    float* bcB  = F + off; off += SZ_BC;
    float* bsB  = F + off; off += SZ_BC;
    float* wts  = F + off; off += SZ_W;
    float* ha   = F + off; off += SZ_H;
    float* hb   = F + off; off += SZ_H;
    float* g    = F + off; off += SZ_G;
    float* part = F + off; off += SZ_PART;
    float* xq   = F + off; off += SZ_XQ;
    float* wf   = F + off; off += SZ_WF;
    float* f0   = F + off; off += SZ_F0;
    int* I      = (int*)(F + off);
    int* cnt    = I;
    int* rowptr = I + 80000;
    int* cur    = I + 80000 + 80016;
    int* csre   = cur + 80000;

    hipMemsetAsync(cnt, 0, (size_t)B_*N_*sizeof(int), stream);
    basis_kernel<<<(B_*N_+255)/256, 256, 0, stream>>>(nodes, nw, modes, latent, bcB, bsB, wts);
    fc0_kernel  <<<(B_*N_+255)/256, 256, 0, stream>>>(x, fc0w, fc0b, ha);
    hist_kernel <<<(B_*E_+255)/256, 256, 0, stream>>>(edges, cnt);
    scan_kernel <<<B_, 256, 0, stream>>>(cnt, rowptr, cur);
    fill_kernel <<<(B_*E_+255)/256, 256, 0, stream>>>(edges, cur, csre);

    float* hc = ha; float* hn = hb;
    for (int l=0; l<3; ++l){
        stageA_kernel<<<dim3(ABLK,B_), 256, 0, stream>>>(hc, bcB, bsB, wts, part);
        reducePart_kernel<<<(B_*C_*65+255)/256, 256, 0, stream>>>(part, xq);
        mix_kernel<<<dim3(C_,B_), 64, 0, stream>>>(
            xq, swc + (size_t)l*C_*C_*K_, sws + (size_t)l*C_*C_*K_,
            sw0 + (size_t)l*C_*C_, wf, f0);
        grad_kernel<<<dim3(N_/2,B_), 256, 0, stream>>>(hc, edges, egw, rowptr, csre, g);
        gemm_kernel<<<dim3((N_+63)/64,B_), 256, 0, stream>>>(
            hc, g, bcB, bsB,
            ww + (size_t)l*C_*C_, wb + (size_t)l*C_,
            gw + (size_t)l*C_*C_*3, gb + (size_t)l*C_,
            wf, f0, hn, (l<2) ? 1 : 0);
        float* t = hc; hc = hn; hn = t;
    }
    final_kernel<<<dim3((N_+63)/64,B_), 256, 0, stream>>>(hc, fc1w, fc1b, fc2w, fc2b, out);
}

// Round 2
// 1464.450 us; speedup vs baseline: 1.2628x; 1.2628x over previous
//
#include <hip/hip_runtime.h>
#include <math.h>

#define B_ 4
#define N_ 20000
#define E_ 100000
#define C_ 128
#define K_ 32
#define ABLK 64      // stage-A blocks per batch
#define NPB_A 313    // nodes per stage-A block (64*313 >= 20000)

typedef __attribute__((ext_vector_type(8))) short short8;
typedef __attribute__((ext_vector_type(4))) float floatx4;

__device__ __forceinline__ float gelu_exact(float x){
    return 0.5f * x * (1.0f + erff(x * 0.70710678118654752f));
}

__device__ __forceinline__ unsigned short f2bf(float f){
    unsigned int u = __builtin_bit_cast(unsigned int, f);
    u += 0x7FFFu + ((u >> 16) & 1u);   // RNE
    return (unsigned short)(u >> 16);
}
__device__ __forceinline__ unsigned int pack2(float a, float b){
    return (unsigned int)f2bf(a) | ((unsigned int)f2bf(b) << 16);
}
__device__ __forceinline__ float bf2f(unsigned short u){
    unsigned int v = ((unsigned int)u) << 16;
    return __builtin_bit_cast(float, v);
}

// ---------------- setup kernels ----------------

__global__ __launch_bounds__(256) void basis_kernel(
    const float* __restrict__ nodes, const float* __restrict__ nw,
    const float* __restrict__ modes, const float* __restrict__ latent,
    unsigned int* __restrict__ bcu, unsigned int* __restrict__ bsu,
    float* __restrict__ wts)
{
    int idx = blockIdx.x*256 + threadIdx.x;
    if (idx >= B_*N_) return;
    float iL0 = 0.5f + 1.5f/(1.f+expf(-latent[0]));
    float iL1 = 0.5f + 1.5f/(1.f+expf(-latent[1]));
    float iL2 = 0.5f + 1.5f/(1.f+expf(-latent[2]));
    float p0 = nodes[(size_t)idx*3+0]*iL0;
    float p1 = nodes[(size_t)idx*3+1]*iL1;
    float p2 = nodes[(size_t)idx*3+2]*iL2;
    #pragma unroll
    for (int k=0;k<K_;k+=2){
        float t0 = p0*modes[k*3+0]     + p1*modes[k*3+1]     + p2*modes[k*3+2];
        float t1 = p0*modes[(k+1)*3+0] + p1*modes[(k+1)*3+1] + p2*modes[(k+1)*3+2];
        bcu[(size_t)idx*16 + (k>>1)] = pack2(cosf(t0), cosf(t1));
        bsu[(size_t)idx*16 + (k>>1)] = pack2(sinf(t0), sinf(t1));
    }
    wts[idx] = nw[idx];
}

__global__ __launch_bounds__(256) void fc0_kernel(
    const float* __restrict__ x, const float* __restrict__ w,
    const float* __restrict__ bvec, float* __restrict__ h)
{
    int idx = blockIdx.x*256 + threadIdx.x;
    if (idx >= B_*N_) return;
    float x0 = x[(size_t)idx*3+0], x1 = x[(size_t)idx*3+1], x2 = x[(size_t)idx*3+2];
    float* hr = h + (size_t)idx*C_;
    for (int c=0;c<C_;c+=4){
        float4 v;
        v.x = bvec[c+0] + x0*w[(c+0)*3] + x1*w[(c+0)*3+1] + x2*w[(c+0)*3+2];
        v.y = bvec[c+1] + x0*w[(c+1)*3] + x1*w[(c+1)*3+1] + x2*w[(c+1)*3+2];
        v.z = bvec[c+2] + x0*w[(c+2)*3] + x1*w[(c+2)*3+1] + x2*w[(c+2)*3+2];
        v.w = bvec[c+3] + x0*w[(c+3)*3] + x1*w[(c+3)*3+1] + x2*w[(c+3)*3+2];
        *(float4*)(hr+c) = v;
    }
}

// ---------------- CSR build ----------------

__global__ __launch_bounds__(256) void hist_kernel(
    const int* __restrict__ edges, int* __restrict__ cnt)
{
    int idx = blockIdx.x*256 + threadIdx.x;
    if (idx >= B_*E_) return;
    int b = idx / E_;
    int t = edges[(size_t)idx*2];
    atomicAdd(cnt + b*N_ + t, 1);
}

__global__ __launch_bounds__(256) void scan_kernel(
    const int* __restrict__ cnt, int* __restrict__ rowptr, int* __restrict__ cur)
{
    __shared__ int sd[256];
    int b = blockIdx.x, tid = threadIdx.x;
    int run = 0;
    for (int base=0; base<N_; base+=256){
        int n = base + tid;
        int v = (n<N_) ? cnt[b*N_+n] : 0;
        sd[tid] = v; __syncthreads();
        #pragma unroll
        for (int off=1; off<256; off<<=1){
            int t = (tid>=off) ? sd[tid-off] : 0;
            __syncthreads();
            sd[tid] += t;
            __syncthreads();
        }
        if (n<N_){
            int excl = run + sd[tid] - v;
            rowptr[b*(N_+1)+n] = excl;
            cur[b*N_+n] = excl;
        }
        run += sd[255];
        __syncthreads();
    }
    if (tid==0) rowptr[b*(N_+1)+N_] = run;
}

__global__ __launch_bounds__(256) void fill_kernel(
    const int* __restrict__ edges, int* __restrict__ cur, int* __restrict__ csre)
{
    int idx = blockIdx.x*256 + threadIdx.x;
    if (idx >= B_*E_) return;
    int b = idx / E_, e = idx - b*E_;
    int t = edges[(size_t)idx*2];
    int pos = atomicAdd(cur + b*N_ + t, 1);
    csre[(size_t)b*E_ + pos] = e;
}

// ---------------- per-layer: spectral reduce (stage A) ----------------

__global__ __launch_bounds__(256) void stageA_kernel(
    const float* __restrict__ h, const unsigned short* __restrict__ bcb,
    const unsigned short* __restrict__ bsb, const float* __restrict__ wts,
    float* __restrict__ part)
{
    __shared__ float lbc[32*K_], lbs[32*K_], lw[32];
    int b = blockIdx.y, blk = blockIdx.x;
    int n0base = blk*NPB_A;
    int nEnd = min(N_, n0base + NPB_A);
    int tid = threadIdx.x;
    int c = tid & 127, half = tid >> 7, kOff = half*16;
    float aC[16], aS[16], a0 = 0.f;
    #pragma unroll
    for (int kk=0;kk<16;kk++){ aC[kk]=0.f; aS[kk]=0.f; }
    size_t bN = (size_t)b*N_;
    for (int n0 = n0base; n0 < nEnd; n0 += 32){
        for (int j = tid; j < 32*K_; j += 256){
            int node = n0 + (j>>5); int kk = j & 31;
            float vc=0.f, vs=0.f;
            if (node < nEnd){
                vc = bf2f(bcb[(bN+node)*K_+kk]);
                vs = bf2f(bsb[(bN+node)*K_+kk]);
            }
            lbc[j]=vc; lbs[j]=vs;
        }
        if (tid < 32){ int node = n0+tid; lw[tid] = (node<nEnd) ? wts[bN+node] : 0.f; }
        __syncthreads();
        int jmax = min(32, nEnd - n0);
        for (int j=0;j<jmax;j++){
            float hw = h[(bN + n0 + j)*C_ + c] * lw[j];
            #pragma unroll
            for (int kk=0;kk<16;kk++){
                aC[kk] += hw * lbc[j*K_+kOff+kk];
                aS[kk] += hw * lbs[j*K_+kOff+kk];
            }
            a0 += hw;
        }
        __syncthreads();
    }
    size_t base = (((size_t)b*ABLK + blk)*C_ + c)*65;
    #pragma unroll
    for (int kk=0;kk<16;kk++){
        part[base + kOff + kk]      = aC[kk];
        part[base + 32 + kOff + kk] = aS[kk];
    }
    if (half==0) part[base+64] = a0;
}

__global__ __launch_bounds__(256) void reducePart_kernel(
    const float* __restrict__ part, float* __restrict__ xq)
{
    int idx = blockIdx.x*256 + threadIdx.x;
    if (idx >= B_*C_*65) return;
    int b = idx / (C_*65);
    int r = idx - b*C_*65;
    float s = 0.f;
    for (int blk=0; blk<ABLK; blk++)
        s += part[((size_t)(b*ABLK+blk))*C_*65 + r];
    xq[idx] = s;
}

// ---------------- per-layer: mode mixing (tiny) ----------------

__global__ __launch_bounds__(64) void mix_kernel(
    const float* __restrict__ xq, const float* __restrict__ swc_l,
    const float* __restrict__ sws_l, const float* __restrict__ sw0_l,
    float* __restrict__ wf, float* __restrict__ f0)
{
    __shared__ float s64[64];
    int o = blockIdx.x, b = blockIdx.y, t = threadIdx.x;
    int k = t & 31; bool isS = t >= 32;
    const float* xqb = xq + (size_t)b*C_*65;
    float acc = 0.f;
    for (int c=0;c<C_;c++){
        float xc = xqb[c*65 + k], xs = xqb[c*65 + 32 + k];
        float wc = swc_l[((size_t)c*C_+o)*K_ + k];
        float ws = sws_l[((size_t)c*C_+o)*K_ + k];
        acc += isS ? (xs*wc + xc*ws) : (xc*wc - xs*ws);
    }
    wf[((size_t)b*C_+o)*64 + t] = isS ? -2.f*acc : 2.f*acc;
    float p = xqb[t*65+64]      * sw0_l[(size_t)t*C_+o]
            + xqb[(t+64)*65+64] * sw0_l[(size_t)(t+64)*C_+o];
    s64[t] = p; __syncthreads();
    if (t==0){
        float s=0.f;
        for (int i=0;i<64;i++) s += s64[i];
        f0[b*C_+o] = s;
    }
}

// ---------------- per-layer: gradient gather (CSR), bf16 output ----------------

__global__ __launch_bounds__(256) void grad_kernel(
    const float* __restrict__ h, const int* __restrict__ edges,
    const float* __restrict__ egw, const int* __restrict__ rowptr,
    const int* __restrict__ csre, unsigned short* __restrict__ g)
{
    int b = blockIdx.y;
    int n = blockIdx.x*2 + (threadIdx.x >> 7);
    int c = threadIdx.x & 127;
    size_t bN = (size_t)b*N_;
    int r0 = rowptr[b*(N_+1)+n], r1 = rowptr[b*(N_+1)+n+1];
    float hc = h[(bN+n)*C_ + c];
    float a0=0.f, a1=0.f, a2=0.f;
    for (int i=r0;i<r1;i++){
        int e = csre[(size_t)b*E_ + i];
        size_t eb = (size_t)b*E_ + e;
        int src = edges[eb*2 + 1];
        float w0 = egw[eb*3+0], w1 = egw[eb*3+1], w2 = egw[eb*3+2];
        float d = h[(bN+src)*C_ + c] - hc;
        a0 += w0*d; a1 += w1*d; a2 += w2*d;
    }
    unsigned short* gr = g + (bN+n)*(size_t)384 + c*3;
    gr[0]=f2bf(a0); gr[1]=f2bf(a1); gr[2]=f2bf(a2);
}

// ---------------- per-layer: fused MFMA GEMM (K=576) + epilogue ----------------
// out[b,n,o] = sum_k A[b,n,k]*W[b,o,k] + wb[o]+gb[o]+f0[b,o]  (gelu if not last)
// A = [h(128) | g(384) | bc(32) | bs(32)] (bf16),  W = [ww | gw | wf] (bf16)
// block: 64n x 128o, K chunks of 64; 4 waves, each 4 m-tiles x 2 o-tiles of 16x16x32

__global__ __launch_bounds__(256) void gemm_kernel(
    const float* __restrict__ h_in, const unsigned short* __restrict__ g,
    const unsigned short* __restrict__ bcb, const unsigned short* __restrict__ bsb,
    const float* __restrict__ ww_l, const float* __restrict__ wb_l,
    const float* __restrict__ gw_l, const float* __restrict__ gb_l,
    const float* __restrict__ wf, const float* __restrict__ f0,
    float* __restrict__ h_out, int apply_gelu)
{
    __shared__ unsigned short As[64*72];   // [n][k], row stride 72 bf16 (144 B)
    __shared__ unsigned short Ws[128*72];  // [o][k], row stride 72 bf16
    int b = blockIdx.y;
    int nb0 = blockIdx.x*64;
    int tid = threadIdx.x;
    int a_n = tid>>2, a_s = tid&3;     // A staging: row n, 16-elem segment
    int w_o = tid>>1, w_h = tid&1;     // W staging: row o, 32-elem half
    int wv = tid>>6, lane = tid&63, l15 = lane&15, quad = lane>>4;
    floatx4 acc[4][2];
    #pragma unroll
    for (int mt=0;mt<4;mt++)
        #pragma unroll
        for (int ot=0;ot<2;ot++) acc[mt][ot] = (floatx4){0.f,0.f,0.f,0.f};
    size_t bN = (size_t)b*N_;
    int gn = nb0 + a_n; bool av = gn < N_;
    size_t row = bN + (size_t)(av ? gn : 0);
    const float* hrow = h_in + row*C_;
    const unsigned short* grow  = g   + row*384;
    const unsigned short* bcrow = bcb + row*K_;
    const unsigned short* bsrow = bsb + row*K_;

    for (int ch=0; ch<9; ++ch){
        // ---- stage A: 16 bf16 per thread ----
        uint4 v0 = make_uint4(0,0,0,0), v1 = make_uint4(0,0,0,0);
        if (av){
            if (ch < 2){
                const float4* p = (const float4*)(hrow + ch*64 + a_s*16);
                float4 fa = p[0], fb = p[1], fc_ = p[2], fd = p[3];
                v0 = make_uint4(pack2(fa.x,fa.y), pack2(fa.z,fa.w),
                                pack2(fb.x,fb.y), pack2(fb.z,fb.w));
                v1 = make_uint4(pack2(fc_.x,fc_.y), pack2(fc_.z,fc_.w),
                                pack2(fd.x,fd.y), pack2(fd.z,fd.w));
            } else if (ch < 8){
                const uint4* p = (const uint4*)(grow + (ch-2)*64 + a_s*16);
                v0 = p[0]; v1 = p[1];
            } else {
                const uint4* p = (a_s < 2) ? (const uint4*)(bcrow + a_s*16)
                                           : (const uint4*)(bsrow + (a_s-2)*16);
                v0 = p[0]; v1 = p[1];
            }
        }
        *(uint4*)&As[a_n*72 + a_s*16]     = v0;
        *(uint4*)&As[a_n*72 + a_s*16 + 8] = v1;
        // ---- stage W: 32 bf16 per thread ----
        #pragma unroll
        for (int i=0;i<8;i++){
            int kl = w_h*32 + i*4;
            float4 v;
            if (ch<2)      v = *(const float4*)(ww_l + (size_t)w_o*C_  + ch*64 + kl);
            else if (ch<8) v = *(const float4*)(gw_l + (size_t)w_o*384 + (ch-2)*64 + kl);
            else           v = *(const float4*)(wf + ((size_t)b*C_ + w_o)*64 + kl);
            uint2 u; u.x = pack2(v.x,v.y); u.y = pack2(v.z,v.w);
            *(uint2*)&Ws[w_o*72 + kl] = u;
        }
        __syncthreads();
        #pragma unroll
        for (int ks=0; ks<2; ks++){
            short8 bfr[2];
            #pragma unroll
            for (int ot=0; ot<2; ot++){
                int o = wv*32 + ot*16 + l15;
                bfr[ot] = *(const short8*)&Ws[o*72 + ks*32 + quad*8];
            }
            #pragma unroll
            for (int mt=0; mt<4; mt++){
                short8 af = *(const short8*)&As[(mt*16+l15)*72 + ks*32 + quad*8];
                acc[mt][0] = __builtin_amdgcn_mfma_f32_16x16x32_bf16(af, bfr[0], acc[mt][0], 0,0,0);
                acc[mt][1] = __builtin_amdgcn_mfma_f32_16x16x32_bf16(af, bfr[1], acc[mt][1], 0,0,0);
            }
        }
        __syncthreads();
    }
    float biasv[2]; int oo[2];
    #pragma unroll
    for (int ot=0;ot<2;ot++){
        int o = wv*32 + ot*16 + l15; oo[ot]=o;
        biasv[ot] = wb_l[o] + gb_l[o] + f0[(size_t)b*C_ + o];
    }
    #pragma unroll
    for (int mt=0;mt<4;mt++){
        #pragma unroll
        for (int r=0;r<4;r++){
            int n = nb0 + mt*16 + quad*4 + r;
            if (n < N_){
                #pragma unroll
                for (int ot=0;ot<2;ot++){
                    float vv = acc[mt][ot][r] + biasv[ot];
                    if (apply_gelu) vv = gelu_exact(vv);
                    h_out[(bN+n)*C_ + oo[ot]] = vv;
                }
            }
        }
    }
}

// ---------------- head: fc1 + gelu + fc2 ----------------

__global__ __launch_bounds__(256) void final_kernel(
    const float* __restrict__ h_in,
    const float* __restrict__ fc1w, const float* __restrict__ fc1b,
    const float* __restrict__ fc2w, const float* __restrict__ fc2b,
    float* __restrict__ out)
{
    __shared__ float As[64*68];
    __shared__ float Ws[64*132];
    __shared__ float p2[256];
    int b = blockIdx.y;
    int nb0 = blockIdx.x*64;
    int tid = threadIdx.x;
    int a_n = tid>>2, a_q = tid&3;
    int w_o = tid>>1, w_h = tid&1;
    int o_base = (tid&31)*4, n_base = (tid>>5)*8;
    float acc[8][4];
    #pragma unroll
    for (int j=0;j<8;j++)
        #pragma unroll
        for (int i=0;i<4;i++) acc[j][i]=0.f;
    size_t bN = (size_t)b*N_;
    int gn = nb0 + a_n; bool av = gn < N_;
    size_t row = bN + (size_t)(av ? gn : 0);
    const float* hrow = h_in + row*C_;
    for (int ch=0; ch<2; ++ch){
        #pragma unroll
        for (int i=0;i<4;i++){
            int kl = a_q*16 + i*4;
            float4 v = make_float4(0.f,0.f,0.f,0.f);
            if (av) v = *(const float4*)(hrow + ch*64 + kl);
            As[(kl+0)*68 + a_n] = v.x;
            As[(kl+1)*68 + a_n] = v.y;
            As[(kl+2)*68 + a_n] = v.z;
            As[(kl+3)*68 + a_n] = v.w;
        }
        #pragma unroll
        for (int i=0;i<8;i++){
            int kl = w_h*32 + i*4;
            const float* wp = fc1w + (size_t)w_o*C_ + ch*64 + kl;
            float4 v = *(const float4*)wp;
            Ws[(kl+0)*132 + w_o] = v.x;
            Ws[(kl+1)*132 + w_o] = v.y;
            Ws[(kl+2)*132 + w_o] = v.z;
            Ws[(kl+3)*132 + w_o] = v.w;
        }
        __syncthreads();
        #pragma unroll 4
        for (int kk=0;kk<64;kk++){
            float4 wv = *(const float4*)&Ws[kk*132 + o_base];
            float4 a0 = *(const float4*)&As[kk*68 + n_base];
            float4 a1 = *(const float4*)&As[kk*68 + n_base + 4];
            float avj[8] = {a0.x,a0.y,a0.z,a0.w,a1.x,a1.y,a1.z,a1.w};
            float wvi[4] = {wv.x,wv.y,wv.z,wv.w};
            #pragma unroll
            for (int j=0;j<8;j++)
                #pragma unroll
                for (int i=0;i<4;i++)
                    acc[j][i] += avj[j]*wvi[i];
        }
        __syncthreads();
    }
    #pragma unroll
    for (int j=0;j<8;j++){
        int n_l = n_base + j;
        float4 v;
        v.x = gelu_exact(acc[j][0] + fc1b[o_base+0]);
        v.y = gelu_exact(acc[j][1] + fc1b[o_base+1]);
        v.z = gelu_exact(acc[j][2] + fc1b[o_base+2]);
        v.w = gelu_exact(acc[j][3] + fc1b[o_base+3]);
        *(float4*)&Ws[n_l*132 + o_base] = v;
    }
    __syncthreads();
    int n_l = tid & 63, fq = tid >> 6;
    float p = 0.f;
    for (int f = fq*32; f < fq*32+32; f++)
        p += fc2w[f] * Ws[n_l*132 + f];
    p2[tid] = p; __syncthreads();
    if (tid < 64){
        float s = p2[tid] + p2[tid+64] + p2[tid+128] + p2[tid+192] + fc2b[0];
        int n = nb0 + tid;
        if (n < N_) out[bN + n] = s;
    }
}

// ---------------- launch ----------------

extern "C" void kernel_launch(void* const* d_in, const int* in_sizes, int n_in,
                              void* d_out, int out_size, void* d_ws, size_t ws_size,
                              hipStream_t stream)
{
    const float* x      = (const float*)d_in[0];
    const float* nodes  = (const float*)d_in[2];
    const float* nw     = (const float*)d_in[3];
    const int*   edges  = (const int*)  d_in[4];
    const float* egw    = (const float*)d_in[5];
    const float* modes  = (const float*)d_in[6];
    const float* latent = (const float*)d_in[7];
    const float* fc0w   = (const float*)d_in[8];
    const float* fc0b   = (const float*)d_in[9];
    const float* swc    = (const float*)d_in[10];
    const float* sws    = (const float*)d_in[11];
    const float* sw0    = (const float*)d_in[12];
    const float* ww     = (const float*)d_in[13];
    const float* wb     = (const float*)d_in[14];
    const float* gw     = (const float*)d_in[15];
    const float* gb     = (const float*)d_in[16];
    const float* fc1w   = (const float*)d_in[17];
    const float* fc1b   = (const float*)d_in[18];
    const float* fc2w   = (const float*)d_in[19];
    const float* fc2b   = (const float*)d_in[20];
    float* out = (float*)d_out;

    char* W = (char*)d_ws;
    size_t off = 0;
    unsigned short* bcB = (unsigned short*)(W+off); off += (size_t)B_*N_*K_*2;   // 5.12 MB
    unsigned short* bsB = (unsigned short*)(W+off); off += (size_t)B_*N_*K_*2;
    float* wts  = (float*)(W+off); off += (size_t)B_*N_*4;
    float* ha   = (float*)(W+off); off += (size_t)B_*N_*C_*4;
    float* hb   = (float*)(W+off); off += (size_t)B_*N_*C_*4;
    unsigned short* g = (unsigned short*)(W+off); off += (size_t)B_*N_*C_*3*2;
    float* part = (float*)(W+off); off += (size_t)B_*ABLK*C_*65*4;
    float* xq   = (float*)(W+off); off += (size_t)B_*C_*65*4;
    float* wf   = (float*)(W+off); off += (size_t)B_*C_*64*4;
    float* f0   = (float*)(W+off); off += (size_t)B_*C_*4;
    int* cnt    = (int*)(W+off); off += (size_t)B_*N_*4;
    int* rowptr = (int*)(W+off); off += (size_t)B_*(N_+1)*4 + 16;
    int* cur    = (int*)(W+off); off += (size_t)B_*N_*4;
    int* csre   = (int*)(W+off);

    hipMemsetAsync(cnt, 0, (size_t)B_*N_*sizeof(int), stream);
    basis_kernel<<<(B_*N_+255)/256, 256, 0, stream>>>(
        nodes, nw, modes, latent, (unsigned int*)bcB, (unsigned int*)bsB, wts);
    fc0_kernel  <<<(B_*N_+255)/256, 256, 0, stream>>>(x, fc0w, fc0b, ha);
    hist_kernel <<<(B_*E_+255)/256, 256, 0, stream>>>(edges, cnt);
    scan_kernel <<<B_, 256, 0, stream>>>(cnt, rowptr, cur);
    fill_kernel <<<(B_*E_+255)/256, 256, 0, stream>>>(edges, cur, csre);

    float* hc = ha; float* hn = hb;
    for (int l=0; l<3; ++l){
        stageA_kernel<<<dim3(ABLK,B_), 256, 0, stream>>>(hc, bcB, bsB, wts, part);
        reducePart_kernel<<<(B_*C_*65+255)/256, 256, 0, stream>>>(part, xq);
        mix_kernel<<<dim3(C_,B_), 64, 0, stream>>>(
            xq, swc + (size_t)l*C_*C_*K_, sws + (size_t)l*C_*C_*K_,
            sw0 + (size_t)l*C_*C_, wf, f0);
        grad_kernel<<<dim3(N_/2,B_), 256, 0, stream>>>(hc, edges, egw, rowptr, csre, g);
        gemm_kernel<<<dim3((N_+63)/64,B_), 256, 0, stream>>>(
            hc, g, bcB, bsB,
            ww + (size_t)l*C_*C_, wb + (size_t)l*C_,
            gw + (size_t)l*C_*C_*3, gb + (size_t)l*C_,
            wf, f0, hn, (l<2) ? 1 : 0);
        float* t = hc; hc = hn; hn = t;
    }
    final_kernel<<<dim3((N_+63)/64,B_), 256, 0, stream>>>(hc, fc1w, fc1b, fc2w, fc2b, out);
}

// Round 3
// 1033.279 us; speedup vs baseline: 1.7898x; 1.4173x over previous
//
#include <hip/hip_runtime.h>
#include <math.h>

#define B_ 4
#define N_ 20000
#define E_ 100000
#define C_ 128
#define K_ 32
#define NPAD 20480   // padded node count (multiple of 64)

typedef __attribute__((ext_vector_type(8))) short short8;
typedef __attribute__((ext_vector_type(4))) float floatx4;

__device__ __forceinline__ float gelu_exact(float x){
    return 0.5f * x * (1.0f + erff(x * 0.70710678118654752f));
}

__device__ __forceinline__ unsigned short f2bf(float f){
    unsigned int u = __builtin_bit_cast(unsigned int, f);
    u += 0x7FFFu + ((u >> 16) & 1u);   // RNE
    return (unsigned short)(u >> 16);
}
__device__ __forceinline__ unsigned int pack2(float a, float b){
    return (unsigned int)f2bf(a) | ((unsigned int)f2bf(b) << 16);
}

// ---------------- setup: basis (bc/bs node-major bf16 + weighted transposed wBt) ----------------
// wBt[b][row][n] bf16, row 0:32 = w*bc, 32:64 = w*bs, 64 = w, 65:79 = 0; n in [0,NPAD), zero pad.

__global__ __launch_bounds__(256) void basis_kernel(
    const float* __restrict__ nodes, const float* __restrict__ nw,
    const float* __restrict__ modes, const float* __restrict__ latent,
    unsigned short* __restrict__ bcb, unsigned short* __restrict__ bsb,
    unsigned short* __restrict__ wBt)
{
    __shared__ float lx[64], ly[64], lz[64], lwv[64];
    __shared__ unsigned short lTc[32*64], lTs[32*64];
    int b = blockIdx.y, n0 = blockIdx.x*64;
    int tid = threadIdx.x;
    size_t bN = (size_t)b*N_;
    if (tid < 64){
        int n = n0 + tid;
        float iL0 = 0.5f + 1.5f/(1.f+expf(-latent[0]));
        float iL1 = 0.5f + 1.5f/(1.f+expf(-latent[1]));
        float iL2 = 0.5f + 1.5f/(1.f+expf(-latent[2]));
        if (n < N_){
            lx[tid] = nodes[(bN+n)*3+0]*iL0;
            ly[tid] = nodes[(bN+n)*3+1]*iL1;
            lz[tid] = nodes[(bN+n)*3+2]*iL2;
            lwv[tid] = nw[bN+n];
        } else { lx[tid]=0.f; ly[tid]=0.f; lz[tid]=0.f; lwv[tid]=0.f; }
    }
    __syncthreads();
    int node = tid>>2, k0 = (tid&3)*8;
    float p0 = lx[node], p1 = ly[node], p2 = lz[node], w = lwv[node];
    float cv[8], sv[8];
    #pragma unroll
    for (int i=0;i<8;i++){
        int k = k0+i;
        float t = p0*modes[k*3+0] + p1*modes[k*3+1] + p2*modes[k*3+2];
        cv[i] = cosf(t); sv[i] = sinf(t);
        lTc[k*64 + node] = f2bf(w*cv[i]);
        lTs[k*64 + node] = f2bf(w*sv[i]);
    }
    int gn = n0 + node;
    if (gn < N_){
        uint4 uc = make_uint4(pack2(cv[0],cv[1]), pack2(cv[2],cv[3]),
                              pack2(cv[4],cv[5]), pack2(cv[6],cv[7]));
        uint4 us = make_uint4(pack2(sv[0],sv[1]), pack2(sv[2],sv[3]),
                              pack2(sv[4],sv[5]), pack2(sv[6],sv[7]));
        *(uint4*)&bcb[(bN+gn)*K_ + k0] = uc;
        *(uint4*)&bsb[(bN+gn)*K_ + k0] = us;
    }
    __syncthreads();
    unsigned short wbf = f2bf(1.f); // placeholder, unused
    (void)wbf;
    #pragma unroll
    for (int i=0;i<5;i++){
        int idx = i*256 + tid;   // < 1280
        int row = idx>>4, seg = idx&15;
        unsigned short v0,v1,v2,v3;
        if (row < 32){
            v0=lTc[row*64+seg*4+0]; v1=lTc[row*64+seg*4+1];
            v2=lTc[row*64+seg*4+2]; v3=lTc[row*64+seg*4+3];
        } else if (row < 64){
            int r = row-32;
            v0=lTs[r*64+seg*4+0]; v1=lTs[r*64+seg*4+1];
            v2=lTs[r*64+seg*4+2]; v3=lTs[r*64+seg*4+3];
        } else if (row == 64){
            v0=f2bf(lwv[seg*4+0]); v1=f2bf(lwv[seg*4+1]);
            v2=f2bf(lwv[seg*4+2]); v3=f2bf(lwv[seg*4+3]);
        } else { v0=v1=v2=v3=0; }
        uint2 u;
        u.x = (unsigned int)v0 | ((unsigned int)v1<<16);
        u.y = (unsigned int)v2 | ((unsigned int)v3<<16);
        *(uint2*)&wBt[((size_t)b*80+row)*NPAD + n0 + seg*4] = u;
    }
}

// ---------------- setup: fc0 (writes h f32 + hT bf16) ----------------

__global__ __launch_bounds__(256) void fc0_kernel(
    const float* __restrict__ x, const float* __restrict__ w,
    const float* __restrict__ bvec, float* __restrict__ h,
    unsigned short* __restrict__ hT)
{
    int idx = blockIdx.x*256 + threadIdx.x;
    if (idx >= B_*N_) return;
    int b = idx / N_, n = idx - b*N_;
    float x0 = x[(size_t)idx*3+0], x1 = x[(size_t)idx*3+1], x2 = x[(size_t)idx*3+2];
    float* hr = h + (size_t)idx*C_;
    for (int c=0;c<C_;c+=4){
        float4 v;
        v.x = bvec[c+0] + x0*w[(c+0)*3] + x1*w[(c+0)*3+1] + x2*w[(c+0)*3+2];
        v.y = bvec[c+1] + x0*w[(c+1)*3] + x1*w[(c+1)*3+1] + x2*w[(c+1)*3+2];
        v.z = bvec[c+2] + x0*w[(c+2)*3] + x1*w[(c+2)*3+1] + x2*w[(c+2)*3+2];
        v.w = bvec[c+3] + x0*w[(c+3)*3] + x1*w[(c+3)*3+1] + x2*w[(c+3)*3+2];
        *(float4*)(hr+c) = v;
        hT[((size_t)b*C_+c+0)*NPAD + n] = f2bf(v.x);
        hT[((size_t)b*C_+c+1)*NPAD + n] = f2bf(v.y);
        hT[((size_t)b*C_+c+2)*NPAD + n] = f2bf(v.z);
        hT[((size_t)b*C_+c+3)*NPAD + n] = f2bf(v.w);
    }
}

// ---------------- CSR build ----------------

__global__ __launch_bounds__(256) void hist_kernel(
    const int* __restrict__ edges, int* __restrict__ cnt)
{
    int idx = blockIdx.x*256 + threadIdx.x;
    if (idx >= B_*E_) return;
    int b = idx / E_;
    int t = edges[(size_t)idx*2];
    atomicAdd(cnt + b*N_ + t, 1);
}

__global__ __launch_bounds__(256) void scan_kernel(
    const int* __restrict__ cnt, int* __restrict__ rowptr, int* __restrict__ cur)
{
    __shared__ int sd[256];
    int b = blockIdx.x, tid = threadIdx.x;
    int run = 0;
    for (int base=0; base<N_; base+=256){
        int n = base + tid;
        int v = (n<N_) ? cnt[b*N_+n] : 0;
        sd[tid] = v; __syncthreads();
        #pragma unroll
        for (int off=1; off<256; off<<=1){
            int t = (tid>=off) ? sd[tid-off] : 0;
            __syncthreads();
            sd[tid] += t;
            __syncthreads();
        }
        if (n<N_){
            int excl = run + sd[tid] - v;
            rowptr[b*(N_+1)+n] = excl;
            cur[b*N_+n] = excl;
        }
        run += sd[255];
        __syncthreads();
    }
    if (tid==0) rowptr[b*(N_+1)+N_] = run;
}

__global__ __launch_bounds__(256) void fill_kernel(
    const int* __restrict__ edges, int* __restrict__ cur, int* __restrict__ csre)
{
    int idx = blockIdx.x*256 + threadIdx.x;
    if (idx >= B_*E_) return;
    int b = idx / E_, e = idx - b*E_;
    int t = edges[(size_t)idx*2];
    int pos = atomicAdd(cur + b*N_ + t, 1);
    csre[(size_t)b*E_ + pos] = e;
}

// ---------------- per-layer: spectral reduce as MFMA GEMM ----------------
// part[b][blk][kcol][c] = sum_{n in blk} wBt[b][kcol][n] * hT[b][c][n]
// grid (64, B), 256 thr; block covers 320 nodes = 5 chunks of 64.

__global__ __launch_bounds__(256) void stageA_kernel(
    const unsigned short* __restrict__ hT, const unsigned short* __restrict__ wBt,
    float* __restrict__ part)
{
    __shared__ unsigned short As[80*72];   // [kcol][node], stride 72
    __shared__ unsigned short Bs[128*72];  // [c][node], stride 72
    int b = blockIdx.y, blk = blockIdx.x;
    int tid = threadIdx.x;
    int wv = tid>>6, lane = tid&63, l15 = lane&15, quad = lane>>4;
    floatx4 acc[5][2];
    #pragma unroll
    for (int mt=0;mt<5;mt++){ acc[mt][0]=(floatx4){0,0,0,0}; acc[mt][1]=(floatx4){0,0,0,0}; }
    size_t hbase = (size_t)b*C_*NPAD;
    size_t wbase = (size_t)b*80*NPAD;
    for (int cidx=0; cidx<5; ++cidx){
        int n0c = blk*320 + cidx*64;
        #pragma unroll
        for (int i=0;i<3;i++){
            int idx = i*256 + tid;
            if (idx < 640){
                int row = idx>>3, seg = idx&7;
                uint4 v = *(const uint4*)&wBt[wbase + (size_t)row*NPAD + n0c + seg*8];
                *(uint4*)&As[row*72 + seg*8] = v;
            }
        }
        #pragma unroll
        for (int i=0;i<4;i++){
            int idx = i*256 + tid;
            int row = idx>>3, seg = idx&7;
            int node = n0c + seg*8;
            uint4 v = make_uint4(0,0,0,0);
            if (node < N_)
                v = *(const uint4*)&hT[hbase + (size_t)row*NPAD + node];
            *(uint4*)&Bs[row*72 + seg*8] = v;
        }
        __syncthreads();
        #pragma unroll
        for (int ks=0; ks<2; ks++){
            short8 bfrag[2];
            #pragma unroll
            for (int ot=0;ot<2;ot++)
                bfrag[ot] = *(const short8*)&Bs[(wv*32+ot*16+l15)*72 + ks*32 + quad*8];
            #pragma unroll
            for (int mt=0;mt<5;mt++){
                short8 af = *(const short8*)&As[(mt*16+l15)*72 + ks*32 + quad*8];
                acc[mt][0] = __builtin_amdgcn_mfma_f32_16x16x32_bf16(af, bfrag[0], acc[mt][0], 0,0,0);
                acc[mt][1] = __builtin_amdgcn_mfma_f32_16x16x32_bf16(af, bfrag[1], acc[mt][1], 0,0,0);
            }
        }
        __syncthreads();
    }
    float* pblk = part + ((size_t)(b*64+blk))*80*C_;
    #pragma unroll
    for (int mt=0;mt<5;mt++){
        #pragma unroll
        for (int ot=0;ot<2;ot++){
            int c = wv*32 + ot*16 + l15;
            #pragma unroll
            for (int r=0;r<4;r++){
                int kcol = mt*16 + quad*4 + r;
                pblk[kcol*C_ + c] = acc[mt][ot][r];
            }
        }
    }
}

__global__ __launch_bounds__(256) void reducePart_kernel(
    const float* __restrict__ part, float* __restrict__ xq)
{
    int idx = blockIdx.x*256 + threadIdx.x;
    if (idx >= B_*80*C_) return;
    int b = idx / (80*C_);
    int r = idx - b*80*C_;
    float s = 0.f;
    for (int blk=0; blk<64; blk++)
        s += part[((size_t)(b*64+blk))*80*C_ + r];
    xq[idx] = s;
}

// ---------------- per-layer: mode mixing (tiny) ----------------
// xq layout: [b][row][c], row 0:32 = xc, 32:64 = xs, 64 = x0

__global__ __launch_bounds__(64) void mix_kernel(
    const float* __restrict__ xq, const float* __restrict__ swc_l,
    const float* __restrict__ sws_l, const float* __restrict__ sw0_l,
    float* __restrict__ wf, float* __restrict__ f0)
{
    __shared__ float s64[64];
    int o = blockIdx.x, b = blockIdx.y, t = threadIdx.x;
    int k = t & 31; bool isS = t >= 32;
    const float* xqb = xq + (size_t)b*80*C_;
    float acc = 0.f;
    for (int c=0;c<C_;c++){
        float xc = xqb[k*C_ + c], xs = xqb[(32+k)*C_ + c];
        float wc = swc_l[((size_t)c*C_+o)*K_ + k];
        float ws = sws_l[((size_t)c*C_+o)*K_ + k];
        acc += isS ? (xs*wc + xc*ws) : (xc*wc - xs*ws);
    }
    wf[((size_t)b*C_+o)*64 + t] = isS ? -2.f*acc : 2.f*acc;
    float p = xqb[64*C_ + t]      * sw0_l[(size_t)t*C_+o]
            + xqb[64*C_ + 64 + t] * sw0_l[(size_t)(t+64)*C_+o];
    s64[t] = p; __syncthreads();
    if (t==0){
        float s=0.f;
        for (int i=0;i<64;i++) s += s64[i];
        f0[b*C_+o] = s;
    }
}

// ---------------- per-layer: gradient gather (CSR), bf16 output ----------------

__global__ __launch_bounds__(256) void grad_kernel(
    const float* __restrict__ h, const int* __restrict__ edges,
    const float* __restrict__ egw, const int* __restrict__ rowptr,
    const int* __restrict__ csre, unsigned short* __restrict__ g)
{
    int b = blockIdx.y;
    int n = blockIdx.x*2 + (threadIdx.x >> 7);
    int c = threadIdx.x & 127;
    size_t bN = (size_t)b*N_;
    int r0 = rowptr[b*(N_+1)+n], r1 = rowptr[b*(N_+1)+n+1];
    float hc = h[(bN+n)*C_ + c];
    float a0=0.f, a1=0.f, a2=0.f;
    for (int i=r0;i<r1;i++){
        int e = csre[(size_t)b*E_ + i];
        size_t eb = (size_t)b*E_ + e;
        int src = edges[eb*2 + 1];
        float w0 = egw[eb*3+0], w1 = egw[eb*3+1], w2 = egw[eb*3+2];
        float d = h[(bN+src)*C_ + c] - hc;
        a0 += w0*d; a1 += w1*d; a2 += w2*d;
    }
    unsigned short* gr = g + (bN+n)*(size_t)384 + c*3;
    gr[0]=f2bf(a0); gr[1]=f2bf(a1); gr[2]=f2bf(a2);
}

// ---------------- per-layer: fused MFMA GEMM (K=576) + epilogue ----------------

__global__ __launch_bounds__(256) void gemm_kernel(
    const float* __restrict__ h_in, const unsigned short* __restrict__ g,
    const unsigned short* __restrict__ bcb, const unsigned short* __restrict__ bsb,
    const float* __restrict__ ww_l, const float* __restrict__ wb_l,
    const float* __restrict__ gw_l, const float* __restrict__ gb_l,
    const float* __restrict__ wf, const float* __restrict__ f0,
    float* __restrict__ h_out, unsigned short* __restrict__ hT, int apply_gelu)
{
    __shared__ unsigned short As[64*72];
    __shared__ unsigned short Ws[128*72];
    int b = blockIdx.y;
    int nb0 = blockIdx.x*64;
    int tid = threadIdx.x;
    int a_n = tid>>2, a_s = tid&3;
    int w_o = tid>>1, w_h = tid&1;
    int wv = tid>>6, lane = tid&63, l15 = lane&15, quad = lane>>4;
    floatx4 acc[4][2];
    #pragma unroll
    for (int mt=0;mt<4;mt++)
        #pragma unroll
        for (int ot=0;ot<2;ot++) acc[mt][ot] = (floatx4){0.f,0.f,0.f,0.f};
    size_t bN = (size_t)b*N_;
    int gn = nb0 + a_n; bool av = gn < N_;
    size_t row = bN + (size_t)(av ? gn : 0);
    const float* hrow = h_in + row*C_;
    const unsigned short* grow  = g   + row*384;
    const unsigned short* bcrow = bcb + row*K_;
    const unsigned short* bsrow = bsb + row*K_;

    for (int ch=0; ch<9; ++ch){
        uint4 v0 = make_uint4(0,0,0,0), v1 = make_uint4(0,0,0,0);
        if (av){
            if (ch < 2){
                const float4* p = (const float4*)(hrow + ch*64 + a_s*16);
                float4 fa = p[0], fb = p[1], fc_ = p[2], fd = p[3];
                v0 = make_uint4(pack2(fa.x,fa.y), pack2(fa.z,fa.w),
                                pack2(fb.x,fb.y), pack2(fb.z,fb.w));
                v1 = make_uint4(pack2(fc_.x,fc_.y), pack2(fc_.z,fc_.w),
                                pack2(fd.x,fd.y), pack2(fd.z,fd.w));
            } else if (ch < 8){
                const uint4* p = (const uint4*)(grow + (ch-2)*64 + a_s*16);
                v0 = p[0]; v1 = p[1];
            } else {
                const uint4* p = (a_s < 2) ? (const uint4*)(bcrow + a_s*16)
                                           : (const uint4*)(bsrow + (a_s-2)*16);
                v0 = p[0]; v1 = p[1];
            }
        }
        *(uint4*)&As[a_n*72 + a_s*16]     = v0;
        *(uint4*)&As[a_n*72 + a_s*16 + 8] = v1;
        #pragma unroll
        for (int i=0;i<8;i++){
            int kl = w_h*32 + i*4;
            float4 v;
            if (ch<2)      v = *(const float4*)(ww_l + (size_t)w_o*C_  + ch*64 + kl);
            else if (ch<8) v = *(const float4*)(gw_l + (size_t)w_o*384 + (ch-2)*64 + kl);
            else           v = *(const float4*)(wf + ((size_t)b*C_ + w_o)*64 + kl);
            uint2 u; u.x = pack2(v.x,v.y); u.y = pack2(v.z,v.w);
            *(uint2*)&Ws[w_o*72 + kl] = u;
        }
        __syncthreads();
        #pragma unroll
        for (int ks=0; ks<2; ks++){
            short8 bfr[2];
            #pragma unroll
            for (int ot=0; ot<2; ot++){
                int o = wv*32 + ot*16 + l15;
                bfr[ot] = *(const short8*)&Ws[o*72 + ks*32 + quad*8];
            }
            #pragma unroll
            for (int mt=0; mt<4; mt++){
                short8 af = *(const short8*)&As[(mt*16+l15)*72 + ks*32 + quad*8];
                acc[mt][0] = __builtin_amdgcn_mfma_f32_16x16x32_bf16(af, bfr[0], acc[mt][0], 0,0,0);
                acc[mt][1] = __builtin_amdgcn_mfma_f32_16x16x32_bf16(af, bfr[1], acc[mt][1], 0,0,0);
            }
        }
        __syncthreads();
    }
    float biasv[2]; int oo[2];
    #pragma unroll
    for (int ot=0;ot<2;ot++){
        int o = wv*32 + ot*16 + l15; oo[ot]=o;
        biasv[ot] = wb_l[o] + gb_l[o] + f0[(size_t)b*C_ + o];
    }
    #pragma unroll
    for (int mt=0;mt<4;mt++){
        #pragma unroll
        for (int ot=0;ot<2;ot++){
            int nb = nb0 + mt*16 + quad*4;
            float v4[4];
            #pragma unroll
            for (int r=0;r<4;r++){
                float vv = acc[mt][ot][r] + biasv[ot];
                if (apply_gelu) vv = gelu_exact(vv);
                v4[r] = vv;
                if (nb + r < N_) h_out[(bN+nb+r)*C_ + oo[ot]] = vv;
            }
            if (apply_gelu && nb < N_){
                uint2 u; u.x = pack2(v4[0],v4[1]); u.y = pack2(v4[2],v4[3]);
                *(uint2*)&hT[((size_t)b*C_+oo[ot])*NPAD + nb] = u;
            }
        }
    }
}

// ---------------- head: fc1 + gelu + fc2 ----------------

__global__ __launch_bounds__(256) void final_kernel(
    const float* __restrict__ h_in,
    const float* __restrict__ fc1w, const float* __restrict__ fc1b,
    const float* __restrict__ fc2w, const float* __restrict__ fc2b,
    float* __restrict__ out)
{
    __shared__ float As[64*68];
    __shared__ float Ws[64*132];
    __shared__ float p2[256];
    int b = blockIdx.y;
    int nb0 = blockIdx.x*64;
    int tid = threadIdx.x;
    int a_n = tid>>2, a_q = tid&3;
    int w_o = tid>>1, w_h = tid&1;
    int o_base = (tid&31)*4, n_base = (tid>>5)*8;
    float acc[8][4];
    #pragma unroll
    for (int j=0;j<8;j++)
        #pragma unroll
        for (int i=0;i<4;i++) acc[j][i]=0.f;
    size_t bN = (size_t)b*N_;
    int gn = nb0 + a_n; bool av = gn < N_;
    size_t row = bN + (size_t)(av ? gn : 0);
    const float* hrow = h_in + row*C_;
    for (int ch=0; ch<2; ++ch){
        #pragma unroll
        for (int i=0;i<4;i++){
            int kl = a_q*16 + i*4;
            float4 v = make_float4(0.f,0.f,0.f,0.f);
            if (av) v = *(const float4*)(hrow + ch*64 + kl);
            As[(kl+0)*68 + a_n] = v.x;
            As[(kl+1)*68 + a_n] = v.y;
            As[(kl+2)*68 + a_n] = v.z;
            As[(kl+3)*68 + a_n] = v.w;
        }
        #pragma unroll
        for (int i=0;i<8;i++){
            int kl = w_h*32 + i*4;
            const float* wp = fc1w + (size_t)w_o*C_ + ch*64 + kl;
            float4 v = *(const float4*)wp;
            Ws[(kl+0)*132 + w_o] = v.x;
            Ws[(kl+1)*132 + w_o] = v.y;
            Ws[(kl+2)*132 + w_o] = v.z;
            Ws[(kl+3)*132 + w_o] = v.w;
        }
        __syncthreads();
        #pragma unroll 4
        for (int kk=0;kk<64;kk++){
            float4 wv = *(const float4*)&Ws[kk*132 + o_base];
            float4 a0 = *(const float4*)&As[kk*68 + n_base];
            float4 a1 = *(const float4*)&As[kk*68 + n_base + 4];
            float avj[8] = {a0.x,a0.y,a0.z,a0.w,a1.x,a1.y,a1.z,a1.w};
            float wvi[4] = {wv.x,wv.y,wv.z,wv.w};
            #pragma unroll
            for (int j=0;j<8;j++)
                #pragma unroll
                for (int i=0;i<4;i++)
                    acc[j][i] += avj[j]*wvi[i];
        }
        __syncthreads();
    }
    #pragma unroll
    for (int j=0;j<8;j++){
        int n_l = n_base + j;
        float4 v;
        v.x = gelu_exact(acc[j][0] + fc1b[o_base+0]);
        v.y = gelu_exact(acc[j][1] + fc1b[o_base+1]);
        v.z = gelu_exact(acc[j][2] + fc1b[o_base+2]);
        v.w = gelu_exact(acc[j][3] + fc1b[o_base+3]);
        *(float4*)&Ws[n_l*132 + o_base] = v;
    }
    __syncthreads();
    int n_l = tid & 63, fq = tid >> 6;
    float p = 0.f;
    for (int f = fq*32; f < fq*32+32; f++)
        p += fc2w[f] * Ws[n_l*132 + f];
    p2[tid] = p; __syncthreads();
    if (tid < 64){
        float s = p2[tid] + p2[tid+64] + p2[tid+128] + p2[tid+192] + fc2b[0];
        int n = nb0 + tid;
        if (n < N_) out[bN + n] = s;
    }
}

// ---------------- launch ----------------

extern "C" void kernel_launch(void* const* d_in, const int* in_sizes, int n_in,
                              void* d_out, int out_size, void* d_ws, size_t ws_size,
                              hipStream_t stream)
{
    const float* x      = (const float*)d_in[0];
    const float* nodes  = (const float*)d_in[2];
    const float* nw     = (const float*)d_in[3];
    const int*   edges  = (const int*)  d_in[4];
    const float* egw    = (const float*)d_in[5];
    const float* modes  = (const float*)d_in[6];
    const float* latent = (const float*)d_in[7];
    const float* fc0w   = (const float*)d_in[8];
    const float* fc0b   = (const float*)d_in[9];
    const float* swc    = (const float*)d_in[10];
    const float* sws    = (const float*)d_in[11];
    const float* sw0    = (const float*)d_in[12];
    const float* ww     = (const float*)d_in[13];
    const float* wb     = (const float*)d_in[14];
    const float* gw     = (const float*)d_in[15];
    const float* gb     = (const float*)d_in[16];
    const float* fc1w   = (const float*)d_in[17];
    const float* fc1b   = (const float*)d_in[18];
    const float* fc2w   = (const float*)d_in[19];
    const float* fc2b   = (const float*)d_in[20];
    float* out = (float*)d_out;

    char* W = (char*)d_ws;
    size_t off = 0;
    unsigned short* bcB = (unsigned short*)(W+off); off += (size_t)B_*N_*K_*2;
    unsigned short* bsB = (unsigned short*)(W+off); off += (size_t)B_*N_*K_*2;
    unsigned short* wBt = (unsigned short*)(W+off); off += (size_t)B_*80*NPAD*2;
    unsigned short* hT  = (unsigned short*)(W+off); off += (size_t)B_*C_*NPAD*2;
    float* ha   = (float*)(W+off); off += (size_t)B_*N_*C_*4;
    float* hb   = (float*)(W+off); off += (size_t)B_*N_*C_*4;
    unsigned short* g = (unsigned short*)(W+off); off += (size_t)B_*N_*C_*3*2;
    float* part = (float*)(W+off); off += (size_t)B_*64*80*C_*4;
    float* xq   = (float*)(W+off); off += (size_t)B_*80*C_*4;
    float* wf   = (float*)(W+off); off += (size_t)B_*C_*64*4;
    float* f0   = (float*)(W+off); off += (size_t)B_*C_*4;
    int* cnt    = (int*)(W+off); off += (size_t)B_*N_*4;
    int* rowptr = (int*)(W+off); off += (size_t)B_*(N_+1)*4 + 16;
    int* cur    = (int*)(W+off); off += (size_t)B_*N_*4;
    int* csre   = (int*)(W+off);

    hipMemsetAsync(cnt, 0, (size_t)B_*N_*sizeof(int), stream);
    basis_kernel<<<dim3(NPAD/64, B_), 256, 0, stream>>>(
        nodes, nw, modes, latent, bcB, bsB, wBt);
    fc0_kernel  <<<(B_*N_+255)/256, 256, 0, stream>>>(x, fc0w, fc0b, ha, hT);
    hist_kernel <<<(B_*E_+255)/256, 256, 0, stream>>>(edges, cnt);
    scan_kernel <<<B_, 256, 0, stream>>>(cnt, rowptr, cur);
    fill_kernel <<<(B_*E_+255)/256, 256, 0, stream>>>(edges, cur, csre);

    float* hc = ha; float* hn = hb;
    for (int l=0; l<3; ++l){
        stageA_kernel<<<dim3(64,B_), 256, 0, stream>>>(hT, wBt, part);
        reducePart_kernel<<<(B_*80*C_+255)/256, 256, 0, stream>>>(part, xq);
        mix_kernel<<<dim3(C_,B_), 64, 0, stream>>>(
            xq, swc + (size_t)l*C_*C_*K_, sws + (size_t)l*C_*C_*K_,
            sw0 + (size_t)l*C_*C_, wf, f0);
        grad_kernel<<<dim3(N_/2,B_), 256, 0, stream>>>(hc, edges, egw, rowptr, csre, g);
        gemm_kernel<<<dim3((N_+63)/64,B_), 256, 0, stream>>>(
            hc, g, bcB, bsB,
            ww + (size_t)l*C_*C_, wb + (size_t)l*C_,
            gw + (size_t)l*C_*C_*3, gb + (size_t)l*C_,
            wf, f0, hn, hT, (l<2) ? 1 : 0);
        float* t = hc; hc = hn; hn = t;
    }
    final_kernel<<<dim3((N_+63)/64,B_), 256, 0, stream>>>(hc, fc1w, fc1b, fc2w, fc2b, out);
}

// Round 4
// 793.818 us; speedup vs baseline: 2.3296x; 1.3017x over previous
//
#include <hip/hip_runtime.h>
#include <math.h>

#define B_ 4
#define N_ 20000
#define E_ 100000
#define C_ 128
#define K_ 32
#define NPAD 20480   // padded node count (multiple of 64)

typedef __attribute__((ext_vector_type(8))) short short8;
typedef __attribute__((ext_vector_type(4))) float floatx4;

__device__ __forceinline__ float gelu_exact(float x){
    return 0.5f * x * (1.0f + erff(x * 0.70710678118654752f));
}

__device__ __forceinline__ unsigned short f2bf(float f){
    unsigned int u = __builtin_bit_cast(unsigned int, f);
    u += 0x7FFFu + ((u >> 16) & 1u);   // RNE
    return (unsigned short)(u >> 16);
}
__device__ __forceinline__ unsigned int pack2(float a, float b){
    return (unsigned int)f2bf(a) | ((unsigned int)f2bf(b) << 16);
}
__device__ __forceinline__ float bf2f(unsigned short u){
    unsigned int v = ((unsigned int)u) << 16;
    return __builtin_bit_cast(float, v);
}

// ---------------- setup: basis (bc/bs node-major bf16 + weighted transposed wBt) ----------------
// wBt[b][row][n] bf16, row 0:32 = w*bc, 32:64 = w*bs, 64 = w, 65:79 = 0; n in [0,NPAD), zero pad.

__global__ __launch_bounds__(256) void basis_kernel(
    const float* __restrict__ nodes, const float* __restrict__ nw,
    const float* __restrict__ modes, const float* __restrict__ latent,
    unsigned short* __restrict__ bcb, unsigned short* __restrict__ bsb,
    unsigned short* __restrict__ wBt)
{
    __shared__ float lx[64], ly[64], lz[64], lwv[64];
    __shared__ unsigned short lTc[32*64], lTs[32*64];
    int b = blockIdx.y, n0 = blockIdx.x*64;
    int tid = threadIdx.x;
    size_t bN = (size_t)b*N_;
    if (tid < 64){
        int n = n0 + tid;
        float iL0 = 0.5f + 1.5f/(1.f+expf(-latent[0]));
        float iL1 = 0.5f + 1.5f/(1.f+expf(-latent[1]));
        float iL2 = 0.5f + 1.5f/(1.f+expf(-latent[2]));
        if (n < N_){
            lx[tid] = nodes[(bN+n)*3+0]*iL0;
            ly[tid] = nodes[(bN+n)*3+1]*iL1;
            lz[tid] = nodes[(bN+n)*3+2]*iL2;
            lwv[tid] = nw[bN+n];
        } else { lx[tid]=0.f; ly[tid]=0.f; lz[tid]=0.f; lwv[tid]=0.f; }
    }
    __syncthreads();
    int node = tid>>2, k0 = (tid&3)*8;
    float p0 = lx[node], p1 = ly[node], p2 = lz[node], w = lwv[node];
    float cv[8], sv[8];
    #pragma unroll
    for (int i=0;i<8;i++){
        int k = k0+i;
        float t = p0*modes[k*3+0] + p1*modes[k*3+1] + p2*modes[k*3+2];
        cv[i] = cosf(t); sv[i] = sinf(t);
        lTc[k*64 + node] = f2bf(w*cv[i]);
        lTs[k*64 + node] = f2bf(w*sv[i]);
    }
    int gn = n0 + node;
    if (gn < N_){
        uint4 uc = make_uint4(pack2(cv[0],cv[1]), pack2(cv[2],cv[3]),
                              pack2(cv[4],cv[5]), pack2(cv[6],cv[7]));
        uint4 us = make_uint4(pack2(sv[0],sv[1]), pack2(sv[2],sv[3]),
                              pack2(sv[4],sv[5]), pack2(sv[6],sv[7]));
        *(uint4*)&bcb[(bN+gn)*K_ + k0] = uc;
        *(uint4*)&bsb[(bN+gn)*K_ + k0] = us;
    }
    __syncthreads();
    #pragma unroll
    for (int i=0;i<5;i++){
        int idx = i*256 + tid;   // < 1280
        int row = idx>>4, seg = idx&15;
        unsigned short v0,v1,v2,v3;
        if (row < 32){
            v0=lTc[row*64+seg*4+0]; v1=lTc[row*64+seg*4+1];
            v2=lTc[row*64+seg*4+2]; v3=lTc[row*64+seg*4+3];
        } else if (row < 64){
            int r = row-32;
            v0=lTs[r*64+seg*4+0]; v1=lTs[r*64+seg*4+1];
            v2=lTs[r*64+seg*4+2]; v3=lTs[r*64+seg*4+3];
        } else if (row == 64){
            v0=f2bf(lwv[seg*4+0]); v1=f2bf(lwv[seg*4+1]);
            v2=f2bf(lwv[seg*4+2]); v3=f2bf(lwv[seg*4+3]);
        } else { v0=v1=v2=v3=0; }
        uint2 u;
        u.x = (unsigned int)v0 | ((unsigned int)v1<<16);
        u.y = (unsigned int)v2 | ((unsigned int)v3<<16);
        *(uint2*)&wBt[((size_t)b*80+row)*NPAD + n0 + seg*4] = u;
    }
}

// ---------------- setup: fc0 (writes hN bf16 node-major + hT bf16 c-major) ----------------

__global__ __launch_bounds__(256) void fc0_kernel(
    const float* __restrict__ x, const float* __restrict__ w,
    const float* __restrict__ bvec, unsigned short* __restrict__ hN,
    unsigned short* __restrict__ hT)
{
    int idx = blockIdx.x*256 + threadIdx.x;
    if (idx >= B_*N_) return;
    int b = idx / N_, n = idx - b*N_;
    float x0 = x[(size_t)idx*3+0], x1 = x[(size_t)idx*3+1], x2 = x[(size_t)idx*3+2];
    unsigned short* hr = hN + (size_t)idx*C_;
    for (int c=0;c<C_;c+=4){
        float4 v;
        v.x = bvec[c+0] + x0*w[(c+0)*3] + x1*w[(c+0)*3+1] + x2*w[(c+0)*3+2];
        v.y = bvec[c+1] + x0*w[(c+1)*3] + x1*w[(c+1)*3+1] + x2*w[(c+1)*3+2];
        v.z = bvec[c+2] + x0*w[(c+2)*3] + x1*w[(c+2)*3+1] + x2*w[(c+2)*3+2];
        v.w = bvec[c+3] + x0*w[(c+3)*3] + x1*w[(c+3)*3+1] + x2*w[(c+3)*3+2];
        uint2 u; u.x = pack2(v.x,v.y); u.y = pack2(v.z,v.w);
        *(uint2*)(hr+c) = u;
        hT[((size_t)b*C_+c+0)*NPAD + n] = f2bf(v.x);
        hT[((size_t)b*C_+c+1)*NPAD + n] = f2bf(v.y);
        hT[((size_t)b*C_+c+2)*NPAD + n] = f2bf(v.z);
        hT[((size_t)b*C_+c+3)*NPAD + n] = f2bf(v.w);
    }
}

// ---------------- CSR build ----------------

__global__ __launch_bounds__(256) void hist_kernel(
    const int* __restrict__ edges, int* __restrict__ cnt)
{
    int idx = blockIdx.x*256 + threadIdx.x;
    if (idx >= B_*E_) return;
    int b = idx / E_;
    int t = edges[(size_t)idx*2];
    atomicAdd(cnt + b*N_ + t, 1);
}

__global__ __launch_bounds__(256) void scan_kernel(
    const int* __restrict__ cnt, int* __restrict__ rowptr, int* __restrict__ cur)
{
    __shared__ int sd[256];
    int b = blockIdx.x, tid = threadIdx.x;
    int run = 0;
    for (int base=0; base<N_; base+=256){
        int n = base + tid;
        int v = (n<N_) ? cnt[b*N_+n] : 0;
        sd[tid] = v; __syncthreads();
        #pragma unroll
        for (int off=1; off<256; off<<=1){
            int t = (tid>=off) ? sd[tid-off] : 0;
            __syncthreads();
            sd[tid] += t;
            __syncthreads();
        }
        if (n<N_){
            int excl = run + sd[tid] - v;
            rowptr[b*(N_+1)+n] = excl;
            cur[b*N_+n] = excl;
        }
        run += sd[255];
        __syncthreads();
    }
    if (tid==0) rowptr[b*(N_+1)+N_] = run;
}

__global__ __launch_bounds__(256) void fill_kernel(
    const int* __restrict__ edges, int* __restrict__ cur, int* __restrict__ csre)
{
    int idx = blockIdx.x*256 + threadIdx.x;
    if (idx >= B_*E_) return;
    int b = idx / E_, e = idx - b*E_;
    int t = edges[(size_t)idx*2];
    int pos = atomicAdd(cur + b*N_ + t, 1);
    csre[(size_t)b*E_ + pos] = e;
}

// ---------------- per-layer: spectral reduce as MFMA GEMM ----------------

__global__ __launch_bounds__(256) void stageA_kernel(
    const unsigned short* __restrict__ hT, const unsigned short* __restrict__ wBt,
    float* __restrict__ part)
{
    __shared__ unsigned short As[80*72];   // [kcol][node], stride 72
    __shared__ unsigned short Bs[128*72];  // [c][node], stride 72
    int b = blockIdx.y, blk = blockIdx.x;
    int tid = threadIdx.x;
    int wv = tid>>6, lane = tid&63, l15 = lane&15, quad = lane>>4;
    floatx4 acc[5][2];
    #pragma unroll
    for (int mt=0;mt<5;mt++){ acc[mt][0]=(floatx4){0,0,0,0}; acc[mt][1]=(floatx4){0,0,0,0}; }
    size_t hbase = (size_t)b*C_*NPAD;
    size_t wbase = (size_t)b*80*NPAD;
    for (int cidx=0; cidx<5; ++cidx){
        int n0c = blk*320 + cidx*64;
        #pragma unroll
        for (int i=0;i<3;i++){
            int idx = i*256 + tid;
            if (idx < 640){
                int row = idx>>3, seg = idx&7;
                uint4 v = *(const uint4*)&wBt[wbase + (size_t)row*NPAD + n0c + seg*8];
                *(uint4*)&As[row*72 + seg*8] = v;
            }
        }
        #pragma unroll
        for (int i=0;i<4;i++){
            int idx = i*256 + tid;
            int row = idx>>3, seg = idx&7;
            int node = n0c + seg*8;
            uint4 v = make_uint4(0,0,0,0);
            if (node < N_)
                v = *(const uint4*)&hT[hbase + (size_t)row*NPAD + node];
            *(uint4*)&Bs[row*72 + seg*8] = v;
        }
        __syncthreads();
        #pragma unroll
        for (int ks=0; ks<2; ks++){
            short8 bfrag[2];
            #pragma unroll
            for (int ot=0;ot<2;ot++)
                bfrag[ot] = *(const short8*)&Bs[(wv*32+ot*16+l15)*72 + ks*32 + quad*8];
            #pragma unroll
            for (int mt=0;mt<5;mt++){
                short8 af = *(const short8*)&As[(mt*16+l15)*72 + ks*32 + quad*8];
                acc[mt][0] = __builtin_amdgcn_mfma_f32_16x16x32_bf16(af, bfrag[0], acc[mt][0], 0,0,0);
                acc[mt][1] = __builtin_amdgcn_mfma_f32_16x16x32_bf16(af, bfrag[1], acc[mt][1], 0,0,0);
            }
        }
        __syncthreads();
    }
    float* pblk = part + ((size_t)(b*64+blk))*80*C_;
    #pragma unroll
    for (int mt=0;mt<5;mt++){
        #pragma unroll
        for (int ot=0;ot<2;ot++){
            int c = wv*32 + ot*16 + l15;
            #pragma unroll
            for (int r=0;r<4;r++){
                int kcol = mt*16 + quad*4 + r;
                pblk[kcol*C_ + c] = acc[mt][ot][r];
            }
        }
    }
}

__global__ __launch_bounds__(256) void reducePart_kernel(
    const float* __restrict__ part, float* __restrict__ xq)
{
    int idx = blockIdx.x*256 + threadIdx.x;
    if (idx >= B_*80*C_) return;
    int b = idx / (80*C_);
    int r = idx - b*80*C_;
    float s = 0.f;
    for (int blk=0; blk<64; blk++)
        s += part[((size_t)(b*64+blk))*80*C_ + r];
    xq[idx] = s;
}

// ---------------- per-layer: mode mixing (tiny) ----------------

__global__ __launch_bounds__(64) void mix_kernel(
    const float* __restrict__ xq, const float* __restrict__ swc_l,
    const float* __restrict__ sws_l, const float* __restrict__ sw0_l,
    float* __restrict__ wf, float* __restrict__ f0)
{
    __shared__ float s64[64];
    int o = blockIdx.x, b = blockIdx.y, t = threadIdx.x;
    int k = t & 31; bool isS = t >= 32;
    const float* xqb = xq + (size_t)b*80*C_;
    float acc = 0.f;
    for (int c=0;c<C_;c++){
        float xc = xqb[k*C_ + c], xs = xqb[(32+k)*C_ + c];
        float wc = swc_l[((size_t)c*C_+o)*K_ + k];
        float ws = sws_l[((size_t)c*C_+o)*K_ + k];
        acc += isS ? (xs*wc + xc*ws) : (xc*wc - xs*ws);
    }
    wf[((size_t)b*C_+o)*64 + t] = isS ? -2.f*acc : 2.f*acc;
    float p = xqb[64*C_ + t]      * sw0_l[(size_t)t*C_+o]
            + xqb[64*C_ + 64 + t] * sw0_l[(size_t)(t+64)*C_+o];
    s64[t] = p; __syncthreads();
    if (t==0){
        float s=0.f;
        for (int i=0;i<64;i++) s += s64[i];
        f0[b*C_+o] = s;
    }
}

// ---------------- per-layer: gradient gather (CSR), bf16 h rows ----------------
// block: 4 nodes x 64 lanes; each lane handles 2 channels (one uint = 2 bf16).

__global__ __launch_bounds__(256) void grad_kernel(
    const unsigned short* __restrict__ hN, const int* __restrict__ edges,
    const float* __restrict__ egw, const int* __restrict__ rowptr,
    const int* __restrict__ csre, unsigned short* __restrict__ g)
{
    int b = blockIdx.y;
    int n = blockIdx.x*4 + (threadIdx.x >> 6);
    int cp = threadIdx.x & 63;
    size_t bN = (size_t)b*N_;
    int r0 = rowptr[b*(N_+1)+n], r1 = rowptr[b*(N_+1)+n+1];
    unsigned int hcu = *(const unsigned int*)&hN[(bN+n)*C_ + cp*2];
    float hc0 = bf2f((unsigned short)hcu), hc1 = bf2f((unsigned short)(hcu>>16));
    float a00=0.f,a01=0.f,a02=0.f, a10=0.f,a11=0.f,a12=0.f;
    if (r0 < r1){
        int e = csre[(size_t)b*E_ + r0];
        size_t eb = (size_t)b*E_ + e;
        int src = edges[eb*2+1];
        float w0 = egw[eb*3+0], w1 = egw[eb*3+1], w2 = egw[eb*3+2];
        for (int i=r0; i<r1; i++){
            unsigned int su = *(const unsigned int*)&hN[(bN+src)*C_ + cp*2];
            int nsrc = 0; float nw0=0.f, nw1=0.f, nw2=0.f;
            if (i+1 < r1){
                int e2 = csre[(size_t)b*E_ + i+1];
                size_t eb2 = (size_t)b*E_ + e2;
                nsrc = edges[eb2*2+1];
                nw0 = egw[eb2*3+0]; nw1 = egw[eb2*3+1]; nw2 = egw[eb2*3+2];
            }
            float d0 = bf2f((unsigned short)su) - hc0;
            float d1 = bf2f((unsigned short)(su>>16)) - hc1;
            a00 += w0*d0; a01 += w1*d0; a02 += w2*d0;
            a10 += w0*d1; a11 += w1*d1; a12 += w2*d1;
            src = nsrc; w0 = nw0; w1 = nw1; w2 = nw2;
        }
    }
    unsigned short* gr = g + (bN+n)*(size_t)384 + cp*6;
    *(unsigned int*)(gr+0) = pack2(a00,a01);
    *(unsigned int*)(gr+2) = pack2(a02,a10);
    *(unsigned int*)(gr+4) = pack2(a11,a12);
}

// ---------------- per-layer: fused MFMA GEMM (K=576) + epilogue ----------------

__global__ __launch_bounds__(256) void gemm_kernel(
    const unsigned short* __restrict__ hN, const unsigned short* __restrict__ g,
    const unsigned short* __restrict__ bcb, const unsigned short* __restrict__ bsb,
    const float* __restrict__ ww_l, const float* __restrict__ wb_l,
    const float* __restrict__ gw_l, const float* __restrict__ gb_l,
    const float* __restrict__ wf, const float* __restrict__ f0,
    unsigned short* __restrict__ hNo, unsigned short* __restrict__ hT, int apply_gelu)
{
    __shared__ unsigned short As[64*72];
    __shared__ unsigned short Ws[128*72];
    int b = blockIdx.y;
    int nb0 = blockIdx.x*64;
    int tid = threadIdx.x;
    int a_n = tid>>2, a_s = tid&3;
    int w_o = tid>>1, w_h = tid&1;
    int wv = tid>>6, lane = tid&63, l15 = lane&15, quad = lane>>4;
    floatx4 acc[4][2];
    #pragma unroll
    for (int mt=0;mt<4;mt++)
        #pragma unroll
        for (int ot=0;ot<2;ot++) acc[mt][ot] = (floatx4){0.f,0.f,0.f,0.f};
    size_t bN = (size_t)b*N_;
    int gn = nb0 + a_n; bool av = gn < N_;
    size_t row = bN + (size_t)(av ? gn : 0);
    const unsigned short* hrow  = hN + row*C_;
    const unsigned short* grow  = g  + row*384;
    const unsigned short* bcrow = bcb + row*K_;
    const unsigned short* bsrow = bsb + row*K_;

    for (int ch=0; ch<9; ++ch){
        uint4 v0 = make_uint4(0,0,0,0), v1 = make_uint4(0,0,0,0);
        if (av){
            if (ch < 8){
                const uint4* p = (ch<2) ? (const uint4*)(hrow + ch*64 + a_s*16)
                                        : (const uint4*)(grow + (ch-2)*64 + a_s*16);
                v0 = p[0]; v1 = p[1];
            } else {
                const uint4* p = (a_s < 2) ? (const uint4*)(bcrow + a_s*16)
                                           : (const uint4*)(bsrow + (a_s-2)*16);
                v0 = p[0]; v1 = p[1];
            }
        }
        *(uint4*)&As[a_n*72 + a_s*16]     = v0;
        *(uint4*)&As[a_n*72 + a_s*16 + 8] = v1;
        #pragma unroll
        for (int i=0;i<8;i++){
            int kl = w_h*32 + i*4;
            float4 v;
            if (ch<2)      v = *(const float4*)(ww_l + (size_t)w_o*C_  + ch*64 + kl);
            else if (ch<8) v = *(const float4*)(gw_l + (size_t)w_o*384 + (ch-2)*64 + kl);
            else           v = *(const float4*)(wf + ((size_t)b*C_ + w_o)*64 + kl);
            uint2 u; u.x = pack2(v.x,v.y); u.y = pack2(v.z,v.w);
            *(uint2*)&Ws[w_o*72 + kl] = u;
        }
        __syncthreads();
        #pragma unroll
        for (int ks=0; ks<2; ks++){
            short8 bfr[2];
            #pragma unroll
            for (int ot=0; ot<2; ot++){
                int o = wv*32 + ot*16 + l15;
                bfr[ot] = *(const short8*)&Ws[o*72 + ks*32 + quad*8];
            }
            #pragma unroll
            for (int mt=0; mt<4; mt++){
                short8 af = *(const short8*)&As[(mt*16+l15)*72 + ks*32 + quad*8];
                acc[mt][0] = __builtin_amdgcn_mfma_f32_16x16x32_bf16(af, bfr[0], acc[mt][0], 0,0,0);
                acc[mt][1] = __builtin_amdgcn_mfma_f32_16x16x32_bf16(af, bfr[1], acc[mt][1], 0,0,0);
            }
        }
        __syncthreads();
    }
    float biasv[2]; int oo[2];
    #pragma unroll
    for (int ot=0;ot<2;ot++){
        int o = wv*32 + ot*16 + l15; oo[ot]=o;
        biasv[ot] = wb_l[o] + gb_l[o] + f0[(size_t)b*C_ + o];
    }
    #pragma unroll
    for (int mt=0;mt<4;mt++){
        #pragma unroll
        for (int ot=0;ot<2;ot++){
            int nb = nb0 + mt*16 + quad*4;
            float v4[4];
            #pragma unroll
            for (int r=0;r<4;r++){
                float vv = acc[mt][ot][r] + biasv[ot];
                if (apply_gelu) vv = gelu_exact(vv);
                v4[r] = vv;
                if (nb + r < N_) hNo[(bN+nb+r)*C_ + oo[ot]] = f2bf(vv);
            }
            if (apply_gelu && nb < N_){
                uint2 u; u.x = pack2(v4[0],v4[1]); u.y = pack2(v4[2],v4[3]);
                *(uint2*)&hT[((size_t)b*C_+oo[ot])*NPAD + nb] = u;
            }
        }
    }
}

// ---------------- head: fc1 + gelu + fc2 (bf16 h input) ----------------

__global__ __launch_bounds__(256) void final_kernel(
    const unsigned short* __restrict__ hN,
    const float* __restrict__ fc1w, const float* __restrict__ fc1b,
    const float* __restrict__ fc2w, const float* __restrict__ fc2b,
    float* __restrict__ out)
{
    __shared__ float As[64*68];
    __shared__ float Ws[64*132];
    __shared__ float p2[256];
    int b = blockIdx.y;
    int nb0 = blockIdx.x*64;
    int tid = threadIdx.x;
    int a_n = tid>>2, a_q = tid&3;
    int w_o = tid>>1, w_h = tid&1;
    int o_base = (tid&31)*4, n_base = (tid>>5)*8;
    float acc[8][4];
    #pragma unroll
    for (int j=0;j<8;j++)
        #pragma unroll
        for (int i=0;i<4;i++) acc[j][i]=0.f;
    size_t bN = (size_t)b*N_;
    int gn = nb0 + a_n; bool av = gn < N_;
    size_t row = bN + (size_t)(av ? gn : 0);
    const unsigned short* hrow = hN + row*C_;
    for (int ch=0; ch<2; ++ch){
        #pragma unroll
        for (int i=0;i<2;i++){
            int kl = a_q*16 + i*8;
            uint4 u = make_uint4(0,0,0,0);
            if (av) u = *(const uint4*)(hrow + ch*64 + kl);
            As[(kl+0)*68 + a_n] = bf2f((unsigned short)u.x);
            As[(kl+1)*68 + a_n] = bf2f((unsigned short)(u.x>>16));
            As[(kl+2)*68 + a_n] = bf2f((unsigned short)u.y);
            As[(kl+3)*68 + a_n] = bf2f((unsigned short)(u.y>>16));
            As[(kl+4)*68 + a_n] = bf2f((unsigned short)u.z);
            As[(kl+5)*68 + a_n] = bf2f((unsigned short)(u.z>>16));
            As[(kl+6)*68 + a_n] = bf2f((unsigned short)u.w);
            As[(kl+7)*68 + a_n] = bf2f((unsigned short)(u.w>>16));
        }
        #pragma unroll
        for (int i=0;i<8;i++){
            int kl = w_h*32 + i*4;
            const float* wp = fc1w + (size_t)w_o*C_ + ch*64 + kl;
            float4 v = *(const float4*)wp;
            Ws[(kl+0)*132 + w_o] = v.x;
            Ws[(kl+1)*132 + w_o] = v.y;
            Ws[(kl+2)*132 + w_o] = v.z;
            Ws[(kl+3)*132 + w_o] = v.w;
        }
        __syncthreads();
        #pragma unroll 4
        for (int kk=0;kk<64;kk++){
            float4 wv = *(const float4*)&Ws[kk*132 + o_base];
            float4 a0 = *(const float4*)&As[kk*68 + n_base];
            float4 a1 = *(const float4*)&As[kk*68 + n_base + 4];
            float avj[8] = {a0.x,a0.y,a0.z,a0.w,a1.x,a1.y,a1.z,a1.w};
            float wvi[4] = {wv.x,wv.y,wv.z,wv.w};
            #pragma unroll
            for (int j=0;j<8;j++)
                #pragma unroll
                for (int i=0;i<4;i++)
                    acc[j][i] += avj[j]*wvi[i];
        }
        __syncthreads();
    }
    #pragma unroll
    for (int j=0;j<8;j++){
        int n_l = n_base + j;
        float4 v;
        v.x = gelu_exact(acc[j][0] + fc1b[o_base+0]);
        v.y = gelu_exact(acc[j][1] + fc1b[o_base+1]);
        v.z = gelu_exact(acc[j][2] + fc1b[o_base+2]);
        v.w = gelu_exact(acc[j][3] + fc1b[o_base+3]);
        *(float4*)&Ws[n_l*132 + o_base] = v;
    }
    __syncthreads();
    int n_l = tid & 63, fq = tid >> 6;
    float p = 0.f;
    for (int f = fq*32; f < fq*32+32; f++)
        p += fc2w[f] * Ws[n_l*132 + f];
    p2[tid] = p; __syncthreads();
    if (tid < 64){
        float s = p2[tid] + p2[tid+64] + p2[tid+128] + p2[tid+192] + fc2b[0];
        int n = nb0 + tid;
        if (n < N_) out[bN + n] = s;
    }
}

// ---------------- launch ----------------

extern "C" void kernel_launch(void* const* d_in, const int* in_sizes, int n_in,
                              void* d_out, int out_size, void* d_ws, size_t ws_size,
                              hipStream_t stream)
{
    const float* x      = (const float*)d_in[0];
    const float* nodes  = (const float*)d_in[2];
    const float* nw     = (const float*)d_in[3];
    const int*   edges  = (const int*)  d_in[4];
    const float* egw    = (const float*)d_in[5];
    const float* modes  = (const float*)d_in[6];
    const float* latent = (const float*)d_in[7];
    const float* fc0w   = (const float*)d_in[8];
    const float* fc0b   = (const float*)d_in[9];
    const float* swc    = (const float*)d_in[10];
    const float* sws    = (const float*)d_in[11];
    const float* sw0    = (const float*)d_in[12];
    const float* ww     = (const float*)d_in[13];
    const float* wb     = (const float*)d_in[14];
    const float* gw     = (const float*)d_in[15];
    const float* gb     = (const float*)d_in[16];
    const float* fc1w   = (const float*)d_in[17];
    const float* fc1b   = (const float*)d_in[18];
    const float* fc2w   = (const float*)d_in[19];
    const float* fc2b   = (const float*)d_in[20];
    float* out = (float*)d_out;

    char* W = (char*)d_ws;
    size_t off = 0;
    unsigned short* bcB = (unsigned short*)(W+off); off += (size_t)B_*N_*K_*2;
    unsigned short* bsB = (unsigned short*)(W+off); off += (size_t)B_*N_*K_*2;
    unsigned short* wBt = (unsigned short*)(W+off); off += (size_t)B_*80*NPAD*2;
    unsigned short* hT  = (unsigned short*)(W+off); off += (size_t)B_*C_*NPAD*2;
    unsigned short* hNa = (unsigned short*)(W+off); off += (size_t)B_*N_*C_*2;
    unsigned short* hNb = (unsigned short*)(W+off); off += (size_t)B_*N_*C_*2;
    unsigned short* g   = (unsigned short*)(W+off); off += (size_t)B_*N_*C_*3*2;
    float* part = (float*)(W+off); off += (size_t)B_*64*80*C_*4;
    float* xq   = (float*)(W+off); off += (size_t)B_*80*C_*4;
    float* wf   = (float*)(W+off); off += (size_t)B_*C_*64*4;
    float* f0   = (float*)(W+off); off += (size_t)B_*C_*4;
    int* cnt    = (int*)(W+off); off += (size_t)B_*N_*4;
    int* rowptr = (int*)(W+off); off += (size_t)B_*(N_+1)*4 + 16;
    int* cur    = (int*)(W+off); off += (size_t)B_*N_*4;
    int* csre   = (int*)(W+off);

    hipMemsetAsync(cnt, 0, (size_t)B_*N_*sizeof(int), stream);
    basis_kernel<<<dim3(NPAD/64, B_), 256, 0, stream>>>(
        nodes, nw, modes, latent, bcB, bsB, wBt);
    fc0_kernel  <<<(B_*N_+255)/256, 256, 0, stream>>>(x, fc0w, fc0b, hNa, hT);
    hist_kernel <<<(B_*E_+255)/256, 256, 0, stream>>>(edges, cnt);
    scan_kernel <<<B_, 256, 0, stream>>>(cnt, rowptr, cur);
    fill_kernel <<<(B_*E_+255)/256, 256, 0, stream>>>(edges, cur, csre);

    unsigned short* hc = hNa; unsigned short* hn = hNb;
    for (int l=0; l<3; ++l){
        stageA_kernel<<<dim3(64,B_), 256, 0, stream>>>(hT, wBt, part);
        reducePart_kernel<<<(B_*80*C_+255)/256, 256, 0, stream>>>(part, xq);
        mix_kernel<<<dim3(C_,B_), 64, 0, stream>>>(
            xq, swc + (size_t)l*C_*C_*K_, sws + (size_t)l*C_*C_*K_,
            sw0 + (size_t)l*C_*C_, wf, f0);
        grad_kernel<<<dim3(N_/4,B_), 256, 0, stream>>>(hc, edges, egw, rowptr, csre, g);
        gemm_kernel<<<dim3((N_+63)/64,B_), 256, 0, stream>>>(
            hc, g, bcB, bsB,
            ww + (size_t)l*C_*C_, wb + (size_t)l*C_,
            gw + (size_t)l*C_*C_*3, gb + (size_t)l*C_,
            wf, f0, hn, hT, (l<2) ? 1 : 0);
        unsigned short* t = hc; hc = hn; hn = t;
    }
    final_kernel<<<dim3((N_+63)/64,B_), 256, 0, stream>>>(hc, fc1w, fc1b, fc2w, fc2b, out);
}

// Round 5
// 731.575 us; speedup vs baseline: 2.5278x; 1.0851x over previous
//
#include <hip/hip_runtime.h>
#include <math.h>

#define B_ 4
#define N_ 20000
#define E_ 100000
#define C_ 128
#define K_ 32
#define NPAD 20480   // padded node count (multiple of 64)

typedef __attribute__((ext_vector_type(8))) short short8;
typedef __attribute__((ext_vector_type(4))) float floatx4;

__device__ __forceinline__ float gelu_exact(float x){
    return 0.5f * x * (1.0f + erff(x * 0.70710678118654752f));
}

__device__ __forceinline__ unsigned short f2bf(float f){
    unsigned int u = __builtin_bit_cast(unsigned int, f);
    u += 0x7FFFu + ((u >> 16) & 1u);   // RNE
    return (unsigned short)(u >> 16);
}
__device__ __forceinline__ unsigned int pack2(float a, float b){
    return (unsigned int)f2bf(a) | ((unsigned int)f2bf(b) << 16);
}
__device__ __forceinline__ float bf2f(unsigned short u){
    unsigned int v = ((unsigned int)u) << 16;
    return __builtin_bit_cast(float, v);
}

// ---------------- setup: basis (bc/bs node-major bf16 + weighted transposed wBt) ----------------
// wBt[b][row][n] bf16, row 0:32 = w*bc, 32:64 = w*bs, 64 = w, 65:79 = 0; n in [0,NPAD), zero pad.

__global__ __launch_bounds__(256) void basis_kernel(
    const float* __restrict__ nodes, const float* __restrict__ nw,
    const float* __restrict__ modes, const float* __restrict__ latent,
    unsigned short* __restrict__ bcb, unsigned short* __restrict__ bsb,
    unsigned short* __restrict__ wBt)
{
    __shared__ float lx[64], ly[64], lz[64], lwv[64];
    __shared__ unsigned short lTc[32*64], lTs[32*64];
    int b = blockIdx.y, n0 = blockIdx.x*64;
    int tid = threadIdx.x;
    size_t bN = (size_t)b*N_;
    if (tid < 64){
        int n = n0 + tid;
        float iL0 = 0.5f + 1.5f/(1.f+expf(-latent[0]));
        float iL1 = 0.5f + 1.5f/(1.f+expf(-latent[1]));
        float iL2 = 0.5f + 1.5f/(1.f+expf(-latent[2]));
        if (n < N_){
            lx[tid] = nodes[(bN+n)*3+0]*iL0;
            ly[tid] = nodes[(bN+n)*3+1]*iL1;
            lz[tid] = nodes[(bN+n)*3+2]*iL2;
            lwv[tid] = nw[bN+n];
        } else { lx[tid]=0.f; ly[tid]=0.f; lz[tid]=0.f; lwv[tid]=0.f; }
    }
    __syncthreads();
    int node = tid>>2, k0 = (tid&3)*8;
    float p0 = lx[node], p1 = ly[node], p2 = lz[node], w = lwv[node];
    float cv[8], sv[8];
    #pragma unroll
    for (int i=0;i<8;i++){
        int k = k0+i;
        float t = p0*modes[k*3+0] + p1*modes[k*3+1] + p2*modes[k*3+2];
        cv[i] = cosf(t); sv[i] = sinf(t);
        lTc[k*64 + node] = f2bf(w*cv[i]);
        lTs[k*64 + node] = f2bf(w*sv[i]);
    }
    int gn = n0 + node;
    if (gn < N_){
        uint4 uc = make_uint4(pack2(cv[0],cv[1]), pack2(cv[2],cv[3]),
                              pack2(cv[4],cv[5]), pack2(cv[6],cv[7]));
        uint4 us = make_uint4(pack2(sv[0],sv[1]), pack2(sv[2],sv[3]),
                              pack2(sv[4],sv[5]), pack2(sv[6],sv[7]));
        *(uint4*)&bcb[(bN+gn)*K_ + k0] = uc;
        *(uint4*)&bsb[(bN+gn)*K_ + k0] = us;
    }
    __syncthreads();
    #pragma unroll
    for (int i=0;i<5;i++){
        int idx = i*256 + tid;   // < 1280
        int row = idx>>4, seg = idx&15;
        unsigned short v0,v1,v2,v3;
        if (row < 32){
            v0=lTc[row*64+seg*4+0]; v1=lTc[row*64+seg*4+1];
            v2=lTc[row*64+seg*4+2]; v3=lTc[row*64+seg*4+3];
        } else if (row < 64){
            int r = row-32;
            v0=lTs[r*64+seg*4+0]; v1=lTs[r*64+seg*4+1];
            v2=lTs[r*64+seg*4+2]; v3=lTs[r*64+seg*4+3];
        } else if (row == 64){
            v0=f2bf(lwv[seg*4+0]); v1=f2bf(lwv[seg*4+1]);
            v2=f2bf(lwv[seg*4+2]); v3=f2bf(lwv[seg*4+3]);
        } else { v0=v1=v2=v3=0; }
        uint2 u;
        u.x = (unsigned int)v0 | ((unsigned int)v1<<16);
        u.y = (unsigned int)v2 | ((unsigned int)v3<<16);
        *(uint2*)&wBt[((size_t)b*80+row)*NPAD + n0 + seg*4] = u;
    }
}

// ---------------- setup: fc0 (writes hN bf16 node-major + hT bf16 c-major) ----------------

__global__ __launch_bounds__(256) void fc0_kernel(
    const float* __restrict__ x, const float* __restrict__ w,
    const float* __restrict__ bvec, unsigned short* __restrict__ hN,
    unsigned short* __restrict__ hT)
{
    int idx = blockIdx.x*256 + threadIdx.x;
    if (idx >= B_*N_) return;
    int b = idx / N_, n = idx - b*N_;
    float x0 = x[(size_t)idx*3+0], x1 = x[(size_t)idx*3+1], x2 = x[(size_t)idx*3+2];
    unsigned short* hr = hN + (size_t)idx*C_;
    for (int c=0;c<C_;c+=4){
        float4 v;
        v.x = bvec[c+0] + x0*w[(c+0)*3] + x1*w[(c+0)*3+1] + x2*w[(c+0)*3+2];
        v.y = bvec[c+1] + x0*w[(c+1)*3] + x1*w[(c+1)*3+1] + x2*w[(c+1)*3+2];
        v.z = bvec[c+2] + x0*w[(c+2)*3] + x1*w[(c+2)*3+1] + x2*w[(c+2)*3+2];
        v.w = bvec[c+3] + x0*w[(c+3)*3] + x1*w[(c+3)*3+1] + x2*w[(c+3)*3+2];
        uint2 u; u.x = pack2(v.x,v.y); u.y = pack2(v.z,v.w);
        *(uint2*)(hr+c) = u;
        hT[((size_t)b*C_+c+0)*NPAD + n] = f2bf(v.x);
        hT[((size_t)b*C_+c+1)*NPAD + n] = f2bf(v.y);
        hT[((size_t)b*C_+c+2)*NPAD + n] = f2bf(v.z);
        hT[((size_t)b*C_+c+3)*NPAD + n] = f2bf(v.w);
    }
}

// ---------------- CSR build ----------------

__global__ __launch_bounds__(256) void hist_kernel(
    const int* __restrict__ edges, int* __restrict__ cnt)
{
    int idx = blockIdx.x*256 + threadIdx.x;
    if (idx >= B_*E_) return;
    int b = idx / E_;
    int t = edges[(size_t)idx*2];
    atomicAdd(cnt + b*N_ + t, 1);
}

// hierarchical scan: 1024 thr/block, 1 block/batch; each thread owns 20 elems.
__global__ __launch_bounds__(1024) void scan_kernel(
    const int* __restrict__ cnt, int* __restrict__ rowptr, int* __restrict__ cur)
{
    __shared__ int wsum[16];
    int b = blockIdx.x, tid = threadIdx.x;
    int lane = tid & 63, wv = tid >> 6;
    const int CHUNK = 20;
    int start = tid * CHUNK;
    int lc[CHUNK];
    int lsum = 0;
    #pragma unroll
    for (int i=0;i<CHUNK;i++){
        int n = start + i;
        int v = (n < N_) ? cnt[b*N_+n] : 0;
        lc[i] = v; lsum += v;
    }
    int v = lsum;
    #pragma unroll
    for (int off=1; off<64; off<<=1){
        int t = __shfl_up(v, off, 64);
        if (lane >= off) v += t;
    }
    if (lane == 63) wsum[wv] = v;
    __syncthreads();
    if (wv == 0 && lane < 16){
        int wv2 = wsum[lane];
        #pragma unroll
        for (int off=1; off<16; off<<=1){
            int t = __shfl_up(wv2, off, 64);
            if (lane >= off) wv2 += t;
        }
        wsum[lane] = wv2;   // inclusive wave prefix
    }
    __syncthreads();
    int waveoff = (wv == 0) ? 0 : wsum[wv-1];
    int excl = waveoff + v - lsum;
    #pragma unroll
    for (int i=0;i<CHUNK;i++){
        int n = start + i;
        if (n < N_){
            rowptr[b*(N_+1)+n] = excl;
            cur[b*N_+n] = excl;
            excl += lc[i];
        }
    }
    if (tid == 0) rowptr[b*(N_+1)+N_] = E_;
}

__global__ __launch_bounds__(256) void fill_kernel(
    const int* __restrict__ edges, int* __restrict__ cur, int* __restrict__ csre)
{
    int idx = blockIdx.x*256 + threadIdx.x;
    if (idx >= B_*E_) return;
    int b = idx / E_, e = idx - b*E_;
    int t = edges[(size_t)idx*2];
    int pos = atomicAdd(cur + b*N_ + t, 1);
    csre[(size_t)b*E_ + pos] = e;
}

// ---------------- per-layer: spectral reduce as MFMA GEMM ----------------

__global__ __launch_bounds__(256) void stageA_kernel(
    const unsigned short* __restrict__ hT, const unsigned short* __restrict__ wBt,
    float* __restrict__ part)
{
    __shared__ unsigned short As[80*72];   // [kcol][node], stride 72
    __shared__ unsigned short Bs[128*72];  // [c][node], stride 72
    int b = blockIdx.y, blk = blockIdx.x;
    int tid = threadIdx.x;
    int wv = tid>>6, lane = tid&63, l15 = lane&15, quad = lane>>4;
    floatx4 acc[5][2];
    #pragma unroll
    for (int mt=0;mt<5;mt++){ acc[mt][0]=(floatx4){0,0,0,0}; acc[mt][1]=(floatx4){0,0,0,0}; }
    size_t hbase = (size_t)b*C_*NPAD;
    size_t wbase = (size_t)b*80*NPAD;
    for (int cidx=0; cidx<5; ++cidx){
        int n0c = blk*320 + cidx*64;
        #pragma unroll
        for (int i=0;i<3;i++){
            int idx = i*256 + tid;
            if (idx < 640){
                int row = idx>>3, seg = idx&7;
                uint4 v = *(const uint4*)&wBt[wbase + (size_t)row*NPAD + n0c + seg*8];
                *(uint4*)&As[row*72 + seg*8] = v;
            }
        }
        #pragma unroll
        for (int i=0;i<4;i++){
            int idx = i*256 + tid;
            int row = idx>>3, seg = idx&7;
            int node = n0c + seg*8;
            uint4 v = make_uint4(0,0,0,0);
            if (node < N_)
                v = *(const uint4*)&hT[hbase + (size_t)row*NPAD + node];
            *(uint4*)&Bs[row*72 + seg*8] = v;
        }
        __syncthreads();
        #pragma unroll
        for (int ks=0; ks<2; ks++){
            short8 bfrag[2];
            #pragma unroll
            for (int ot=0;ot<2;ot++)
                bfrag[ot] = *(const short8*)&Bs[(wv*32+ot*16+l15)*72 + ks*32 + quad*8];
            #pragma unroll
            for (int mt=0;mt<5;mt++){
                short8 af = *(const short8*)&As[(mt*16+l15)*72 + ks*32 + quad*8];
                acc[mt][0] = __builtin_amdgcn_mfma_f32_16x16x32_bf16(af, bfrag[0], acc[mt][0], 0,0,0);
                acc[mt][1] = __builtin_amdgcn_mfma_f32_16x16x32_bf16(af, bfrag[1], acc[mt][1], 0,0,0);
            }
        }
        __syncthreads();
    }
    float* pblk = part + ((size_t)(b*64+blk))*80*C_;
    #pragma unroll
    for (int mt=0;mt<5;mt++){
        #pragma unroll
        for (int ot=0;ot<2;ot++){
            int c = wv*32 + ot*16 + l15;
            #pragma unroll
            for (int r=0;r<4;r++){
                int kcol = mt*16 + quad*4 + r;
                pblk[kcol*C_ + c] = acc[mt][ot][r];
            }
        }
    }
}

__global__ __launch_bounds__(256) void reducePart_kernel(
    const float* __restrict__ part, float* __restrict__ xq)
{
    int idx = blockIdx.x*256 + threadIdx.x;
    if (idx >= B_*80*C_) return;
    int b = idx / (80*C_);
    int r = idx - b*80*C_;
    float s = 0.f;
    for (int blk=0; blk<64; blk++)
        s += part[((size_t)(b*64+blk))*80*C_ + r];
    xq[idx] = s;
}

// ---------------- per-layer: mode mixing (tiny) ----------------

__global__ __launch_bounds__(64) void mix_kernel(
    const float* __restrict__ xq, const float* __restrict__ swc_l,
    const float* __restrict__ sws_l, const float* __restrict__ sw0_l,
    float* __restrict__ wf, float* __restrict__ f0)
{
    __shared__ float s64[64];
    int o = blockIdx.x, b = blockIdx.y, t = threadIdx.x;
    int k = t & 31; bool isS = t >= 32;
    const float* xqb = xq + (size_t)b*80*C_;
    float acc = 0.f;
    for (int c=0;c<C_;c++){
        float xc = xqb[k*C_ + c], xs = xqb[(32+k)*C_ + c];
        float wc = swc_l[((size_t)c*C_+o)*K_ + k];
        float ws = sws_l[((size_t)c*C_+o)*K_ + k];
        acc += isS ? (xs*wc + xc*ws) : (xc*wc - xs*ws);
    }
    wf[((size_t)b*C_+o)*64 + t] = isS ? -2.f*acc : 2.f*acc;
    float p = xqb[64*C_ + t]      * sw0_l[(size_t)t*C_+o]
            + xqb[64*C_ + 64 + t] * sw0_l[(size_t)(t+64)*C_+o];
    s64[t] = p; __syncthreads();
    if (t==0){
        float s=0.f;
        for (int i=0;i<64;i++) s += s64[i];
        f0[b*C_+o] = s;
    }
}

// ---------------- per-layer: gradient gather (CSR), bf16 h rows ----------------

__global__ __launch_bounds__(256) void grad_kernel(
    const unsigned short* __restrict__ hN, const int* __restrict__ edges,
    const float* __restrict__ egw, const int* __restrict__ rowptr,
    const int* __restrict__ csre, unsigned short* __restrict__ g)
{
    int b = blockIdx.y;
    int n = blockIdx.x*4 + (threadIdx.x >> 6);
    int cp = threadIdx.x & 63;
    size_t bN = (size_t)b*N_;
    int r0 = rowptr[b*(N_+1)+n], r1 = rowptr[b*(N_+1)+n+1];
    unsigned int hcu = *(const unsigned int*)&hN[(bN+n)*C_ + cp*2];
    float hc0 = bf2f((unsigned short)hcu), hc1 = bf2f((unsigned short)(hcu>>16));
    float a00=0.f,a01=0.f,a02=0.f, a10=0.f,a11=0.f,a12=0.f;
    if (r0 < r1){
        int e = csre[(size_t)b*E_ + r0];
        size_t eb = (size_t)b*E_ + e;
        int src = edges[eb*2+1];
        float w0 = egw[eb*3+0], w1 = egw[eb*3+1], w2 = egw[eb*3+2];
        for (int i=r0; i<r1; i++){
            unsigned int su = *(const unsigned int*)&hN[(bN+src)*C_ + cp*2];
            int nsrc = 0; float nw0=0.f, nw1=0.f, nw2=0.f;
            if (i+1 < r1){
                int e2 = csre[(size_t)b*E_ + i+1];
                size_t eb2 = (size_t)b*E_ + e2;
                nsrc = edges[eb2*2+1];
                nw0 = egw[eb2*3+0]; nw1 = egw[eb2*3+1]; nw2 = egw[eb2*3+2];
            }
            float d0 = bf2f((unsigned short)su) - hc0;
            float d1 = bf2f((unsigned short)(su>>16)) - hc1;
            a00 += w0*d0; a01 += w1*d0; a02 += w2*d0;
            a10 += w0*d1; a11 += w1*d1; a12 += w2*d1;
            src = nsrc; w0 = nw0; w1 = nw1; w2 = nw2;
        }
    }
    unsigned short* gr = g + (bN+n)*(size_t)384 + cp*6;
    *(unsigned int*)(gr+0) = pack2(a00,a01);
    *(unsigned int*)(gr+2) = pack2(a02,a10);
    *(unsigned int*)(gr+4) = pack2(a11,a12);
}

// ---------------- per-layer: fused MFMA GEMM (K=576) + epilogue ----------------

__global__ __launch_bounds__(256) void gemm_kernel(
    const unsigned short* __restrict__ hN, const unsigned short* __restrict__ g,
    const unsigned short* __restrict__ bcb, const unsigned short* __restrict__ bsb,
    const float* __restrict__ ww_l, const float* __restrict__ wb_l,
    const float* __restrict__ gw_l, const float* __restrict__ gb_l,
    const float* __restrict__ wf, const float* __restrict__ f0,
    unsigned short* __restrict__ hNo, unsigned short* __restrict__ hT, int apply_gelu)
{
    __shared__ unsigned short As[64*72];
    __shared__ unsigned short Ws[128*72];
    int b = blockIdx.y;
    int nb0 = blockIdx.x*64;
    int tid = threadIdx.x;
    int a_n = tid>>2, a_s = tid&3;
    int w_o = tid>>1, w_h = tid&1;
    int wv = tid>>6, lane = tid&63, l15 = lane&15, quad = lane>>4;
    floatx4 acc[4][2];
    #pragma unroll
    for (int mt=0;mt<4;mt++)
        #pragma unroll
        for (int ot=0;ot<2;ot++) acc[mt][ot] = (floatx4){0.f,0.f,0.f,0.f};
    size_t bN = (size_t)b*N_;
    int gn = nb0 + a_n; bool av = gn < N_;
    size_t row = bN + (size_t)(av ? gn : 0);
    const unsigned short* hrow  = hN + row*C_;
    const unsigned short* grow  = g  + row*384;
    const unsigned short* bcrow = bcb + row*K_;
    const unsigned short* bsrow = bsb + row*K_;

    for (int ch=0; ch<9; ++ch){
        uint4 v0 = make_uint4(0,0,0,0), v1 = make_uint4(0,0,0,0);
        if (av){
            if (ch < 8){
                const uint4* p = (ch<2) ? (const uint4*)(hrow + ch*64 + a_s*16)
                                        : (const uint4*)(grow + (ch-2)*64 + a_s*16);
                v0 = p[0]; v1 = p[1];
            } else {
                const uint4* p = (a_s < 2) ? (const uint4*)(bcrow + a_s*16)
                                           : (const uint4*)(bsrow + (a_s-2)*16);
                v0 = p[0]; v1 = p[1];
            }
        }
        *(uint4*)&As[a_n*72 + a_s*16]     = v0;
        *(uint4*)&As[a_n*72 + a_s*16 + 8] = v1;
        #pragma unroll
        for (int i=0;i<8;i++){
            int kl = w_h*32 + i*4;
            float4 v;
            if (ch<2)      v = *(const float4*)(ww_l + (size_t)w_o*C_  + ch*64 + kl);
            else if (ch<8) v = *(const float4*)(gw_l + (size_t)w_o*384 + (ch-2)*64 + kl);
            else           v = *(const float4*)(wf + ((size_t)b*C_ + w_o)*64 + kl);
            uint2 u; u.x = pack2(v.x,v.y); u.y = pack2(v.z,v.w);
            *(uint2*)&Ws[w_o*72 + kl] = u;
        }
        __syncthreads();
        #pragma unroll
        for (int ks=0; ks<2; ks++){
            short8 bfr[2];
            #pragma unroll
            for (int ot=0; ot<2; ot++){
                int o = wv*32 + ot*16 + l15;
                bfr[ot] = *(const short8*)&Ws[o*72 + ks*32 + quad*8];
            }
            #pragma unroll
            for (int mt=0; mt<4; mt++){
                short8 af = *(const short8*)&As[(mt*16+l15)*72 + ks*32 + quad*8];
                acc[mt][0] = __builtin_amdgcn_mfma_f32_16x16x32_bf16(af, bfr[0], acc[mt][0], 0,0,0);
                acc[mt][1] = __builtin_amdgcn_mfma_f32_16x16x32_bf16(af, bfr[1], acc[mt][1], 0,0,0);
            }
        }
        __syncthreads();
    }
    float biasv[2]; int oo[2];
    #pragma unroll
    for (int ot=0;ot<2;ot++){
        int o = wv*32 + ot*16 + l15; oo[ot]=o;
        biasv[ot] = wb_l[o] + gb_l[o] + f0[(size_t)b*C_ + o];
    }
    #pragma unroll
    for (int mt=0;mt<4;mt++){
        #pragma unroll
        for (int ot=0;ot<2;ot++){
            int nb = nb0 + mt*16 + quad*4;
            float v4[4];
            #pragma unroll
            for (int r=0;r<4;r++){
                float vv = acc[mt][ot][r] + biasv[ot];
                if (apply_gelu) vv = gelu_exact(vv);
                v4[r] = vv;
                if (nb + r < N_) hNo[(bN+nb+r)*C_ + oo[ot]] = f2bf(vv);
            }
            if (apply_gelu && nb < N_){
                uint2 u; u.x = pack2(v4[0],v4[1]); u.y = pack2(v4[2],v4[3]);
                *(uint2*)&hT[((size_t)b*C_+oo[ot])*NPAD + nb] = u;
            }
        }
    }
}

// ---------------- head: fc1 + gelu + fc2 (bf16 h input) ----------------

__global__ __launch_bounds__(256) void final_kernel(
    const unsigned short* __restrict__ hN,
    const float* __restrict__ fc1w, const float* __restrict__ fc1b,
    const float* __restrict__ fc2w, const float* __restrict__ fc2b,
    float* __restrict__ out)
{
    __shared__ float As[64*68];
    __shared__ float Ws[64*132];
    __shared__ float p2[256];
    int b = blockIdx.y;
    int nb0 = blockIdx.x*64;
    int tid = threadIdx.x;
    int a_n = tid>>2, a_q = tid&3;
    int w_o = tid>>1, w_h = tid&1;
    int o_base = (tid&31)*4, n_base = (tid>>5)*8;
    float acc[8][4];
    #pragma unroll
    for (int j=0;j<8;j++)
        #pragma unroll
        for (int i=0;i<4;i++) acc[j][i]=0.f;
    size_t bN = (size_t)b*N_;
    int gn = nb0 + a_n; bool av = gn < N_;
    size_t row = bN + (size_t)(av ? gn : 0);
    const unsigned short* hrow = hN + row*C_;
    for (int ch=0; ch<2; ++ch){
        #pragma unroll
        for (int i=0;i<2;i++){
            int kl = a_q*16 + i*8;
            uint4 u = make_uint4(0,0,0,0);
            if (av) u = *(const uint4*)(hrow + ch*64 + kl);
            As[(kl+0)*68 + a_n] = bf2f((unsigned short)u.x);
            As[(kl+1)*68 + a_n] = bf2f((unsigned short)(u.x>>16));
            As[(kl+2)*68 + a_n] = bf2f((unsigned short)u.y);
            As[(kl+3)*68 + a_n] = bf2f((unsigned short)(u.y>>16));
            As[(kl+4)*68 + a_n] = bf2f((unsigned short)u.z);
            As[(kl+5)*68 + a_n] = bf2f((unsigned short)(u.z>>16));
            As[(kl+6)*68 + a_n] = bf2f((unsigned short)u.w);
            As[(kl+7)*68 + a_n] = bf2f((unsigned short)(u.w>>16));
        }
        #pragma unroll
        for (int i=0;i<8;i++){
            int kl = w_h*32 + i*4;
            const float* wp = fc1w + (size_t)w_o*C_ + ch*64 + kl;
            float4 v = *(const float4*)wp;
            Ws[(kl+0)*132 + w_o] = v.x;
            Ws[(kl+1)*132 + w_o] = v.y;
            Ws[(kl+2)*132 + w_o] = v.z;
            Ws[(kl+3)*132 + w_o] = v.w;
        }
        __syncthreads();
        #pragma unroll 4
        for (int kk=0;kk<64;kk++){
            float4 wv = *(const float4*)&Ws[kk*132 + o_base];
            float4 a0 = *(const float4*)&As[kk*68 + n_base];
            float4 a1 = *(const float4*)&As[kk*68 + n_base + 4];
            float avj[8] = {a0.x,a0.y,a0.z,a0.w,a1.x,a1.y,a1.z,a1.w};
            float wvi[4] = {wv.x,wv.y,wv.z,wv.w};
            #pragma unroll
            for (int j=0;j<8;j++)
                #pragma unroll
                for (int i=0;i<4;i++)
                    acc[j][i] += avj[j]*wvi[i];
        }
        __syncthreads();
    }
    #pragma unroll
    for (int j=0;j<8;j++){
        int n_l = n_base + j;
        float4 v;
        v.x = gelu_exact(acc[j][0] + fc1b[o_base+0]);
        v.y = gelu_exact(acc[j][1] + fc1b[o_base+1]);
        v.z = gelu_exact(acc[j][2] + fc1b[o_base+2]);
        v.w = gelu_exact(acc[j][3] + fc1b[o_base+3]);
        *(float4*)&Ws[n_l*132 + o_base] = v;
    }
    __syncthreads();
    int n_l = tid & 63, fq = tid >> 6;
    float p = 0.f;
    for (int f = fq*32; f < fq*32+32; f++)
        p += fc2w[f] * Ws[n_l*132 + f];
    p2[tid] = p; __syncthreads();
    if (tid < 64){
        float s = p2[tid] + p2[tid+64] + p2[tid+128] + p2[tid+192] + fc2b[0];
        int n = nb0 + tid;
        if (n < N_) out[bN + n] = s;
    }
}

// ---------------- launch ----------------

extern "C" void kernel_launch(void* const* d_in, const int* in_sizes, int n_in,
                              void* d_out, int out_size, void* d_ws, size_t ws_size,
                              hipStream_t stream)
{
    const float* x      = (const float*)d_in[0];
    const float* nodes  = (const float*)d_in[2];
    const float* nw     = (const float*)d_in[3];
    const int*   edges  = (const int*)  d_in[4];
    const float* egw    = (const float*)d_in[5];
    const float* modes  = (const float*)d_in[6];
    const float* latent = (const float*)d_in[7];
    const float* fc0w   = (const float*)d_in[8];
    const float* fc0b   = (const float*)d_in[9];
    const float* swc    = (const float*)d_in[10];
    const float* sws    = (const float*)d_in[11];
    const float* sw0    = (const float*)d_in[12];
    const float* ww     = (const float*)d_in[13];
    const float* wb     = (const float*)d_in[14];
    const float* gw     = (const float*)d_in[15];
    const float* gb     = (const float*)d_in[16];
    const float* fc1w   = (const float*)d_in[17];
    const float* fc1b   = (const float*)d_in[18];
    const float* fc2w   = (const float*)d_in[19];
    const float* fc2b   = (const float*)d_in[20];
    float* out = (float*)d_out;

    char* W = (char*)d_ws;
    size_t off = 0;
    unsigned short* bcB = (unsigned short*)(W+off); off += (size_t)B_*N_*K_*2;
    unsigned short* bsB = (unsigned short*)(W+off); off += (size_t)B_*N_*K_*2;
    unsigned short* wBt = (unsigned short*)(W+off); off += (size_t)B_*80*NPAD*2;
    unsigned short* hT  = (unsigned short*)(W+off); off += (size_t)B_*C_*NPAD*2;
    unsigned short* hNa = (unsigned short*)(W+off); off += (size_t)B_*N_*C_*2;
    unsigned short* hNb = (unsigned short*)(W+off); off += (size_t)B_*N_*C_*2;
    unsigned short* g   = (unsigned short*)(W+off); off += (size_t)B_*N_*C_*3*2;
    float* part = (float*)(W+off); off += (size_t)B_*64*80*C_*4;
    float* xq   = (float*)(W+off); off += (size_t)B_*80*C_*4;
    float* wf   = (float*)(W+off); off += (size_t)B_*C_*64*4;
    float* f0   = (float*)(W+off); off += (size_t)B_*C_*4;
    int* cnt    = (int*)(W+off); off += (size_t)B_*N_*4;
    int* rowptr = (int*)(W+off); off += (size_t)B_*(N_+1)*4 + 16;
    int* cur    = (int*)(W+off); off += (size_t)B_*N_*4;
    int* csre   = (int*)(W+off);

    hipMemsetAsync(cnt, 0, (size_t)B_*N_*sizeof(int), stream);
    basis_kernel<<<dim3(NPAD/64, B_), 256, 0, stream>>>(
        nodes, nw, modes, latent, bcB, bsB, wBt);
    fc0_kernel  <<<(B_*N_+255)/256, 256, 0, stream>>>(x, fc0w, fc0b, hNa, hT);
    hist_kernel <<<(B_*E_+255)/256, 256, 0, stream>>>(edges, cnt);
    scan_kernel <<<B_, 1024, 0, stream>>>(cnt, rowptr, cur);
    fill_kernel <<<(B_*E_+255)/256, 256, 0, stream>>>(edges, cur, csre);

    unsigned short* hc = hNa; unsigned short* hn = hNb;
    for (int l=0; l<3; ++l){
        stageA_kernel<<<dim3(64,B_), 256, 0, stream>>>(hT, wBt, part);
        reducePart_kernel<<<(B_*80*C_+255)/256, 256, 0, stream>>>(part, xq);
        mix_kernel<<<dim3(C_,B_), 64, 0, stream>>>(
            xq, swc + (size_t)l*C_*C_*K_, sws + (size_t)l*C_*C_*K_,
            sw0 + (size_t)l*C_*C_, wf, f0);
        grad_kernel<<<dim3(N_/4,B_), 256, 0, stream>>>(hc, edges, egw, rowptr, csre, g);
        gemm_kernel<<<dim3((N_+63)/64,B_), 256, 0, stream>>>(
            hc, g, bcB, bsB,
            ww + (size_t)l*C_*C_, wb + (size_t)l*C_,
            gw + (size_t)l*C_*C_*3, gb + (size_t)l*C_,
            wf, f0, hn, hT, (l<2) ? 1 : 0);
        unsigned short* t = hc; hc = hn; hn = t;
    }
    final_kernel<<<dim3((N_+63)/64,B_), 256, 0, stream>>>(hc, fc1w, fc1b, fc2w, fc2b, out);
}

// Round 6
// 684.851 us; speedup vs baseline: 2.7003x; 1.0682x over previous
//
#include <hip/hip_runtime.h>
#include <math.h>

#define B_ 4
#define N_ 20000
#define E_ 100000
#define C_ 128
#define K_ 32
#define NPAD 20480   // padded node count (multiple of 64)

typedef __attribute__((ext_vector_type(8))) short short8;
typedef __attribute__((ext_vector_type(4))) float floatx4;

__device__ __forceinline__ float gelu_exact(float x){
    return 0.5f * x * (1.0f + erff(x * 0.70710678118654752f));
}

__device__ __forceinline__ unsigned short f2bf(float f){
    unsigned int u = __builtin_bit_cast(unsigned int, f);
    u += 0x7FFFu + ((u >> 16) & 1u);   // RNE
    return (unsigned short)(u >> 16);
}
__device__ __forceinline__ unsigned int pack2(float a, float b){
    return (unsigned int)f2bf(a) | ((unsigned int)f2bf(b) << 16);
}
__device__ __forceinline__ float bf2f(unsigned short u){
    unsigned int v = ((unsigned int)u) << 16;
    return __builtin_bit_cast(float, v);
}

// ---------------- setup: basis ----------------

__global__ __launch_bounds__(256) void basis_kernel(
    const float* __restrict__ nodes, const float* __restrict__ nw,
    const float* __restrict__ modes, const float* __restrict__ latent,
    unsigned short* __restrict__ bcb, unsigned short* __restrict__ bsb,
    unsigned short* __restrict__ wBt)
{
    __shared__ float lx[64], ly[64], lz[64], lwv[64];
    __shared__ unsigned short lTc[32*64], lTs[32*64];
    int b = blockIdx.y, n0 = blockIdx.x*64;
    int tid = threadIdx.x;
    size_t bN = (size_t)b*N_;
    if (tid < 64){
        int n = n0 + tid;
        float iL0 = 0.5f + 1.5f/(1.f+expf(-latent[0]));
        float iL1 = 0.5f + 1.5f/(1.f+expf(-latent[1]));
        float iL2 = 0.5f + 1.5f/(1.f+expf(-latent[2]));
        if (n < N_){
            lx[tid] = nodes[(bN+n)*3+0]*iL0;
            ly[tid] = nodes[(bN+n)*3+1]*iL1;
            lz[tid] = nodes[(bN+n)*3+2]*iL2;
            lwv[tid] = nw[bN+n];
        } else { lx[tid]=0.f; ly[tid]=0.f; lz[tid]=0.f; lwv[tid]=0.f; }
    }
    __syncthreads();
    int node = tid>>2, k0 = (tid&3)*8;
    float p0 = lx[node], p1 = ly[node], p2 = lz[node], w = lwv[node];
    float cv[8], sv[8];
    #pragma unroll
    for (int i=0;i<8;i++){
        int k = k0+i;
        float t = p0*modes[k*3+0] + p1*modes[k*3+1] + p2*modes[k*3+2];
        cv[i] = cosf(t); sv[i] = sinf(t);
        lTc[k*64 + node] = f2bf(w*cv[i]);
        lTs[k*64 + node] = f2bf(w*sv[i]);
    }
    int gn = n0 + node;
    if (gn < N_){
        uint4 uc = make_uint4(pack2(cv[0],cv[1]), pack2(cv[2],cv[3]),
                              pack2(cv[4],cv[5]), pack2(cv[6],cv[7]));
        uint4 us = make_uint4(pack2(sv[0],sv[1]), pack2(sv[2],sv[3]),
                              pack2(sv[4],sv[5]), pack2(sv[6],sv[7]));
        *(uint4*)&bcb[(bN+gn)*K_ + k0] = uc;
        *(uint4*)&bsb[(bN+gn)*K_ + k0] = us;
    }
    __syncthreads();
    #pragma unroll
    for (int i=0;i<5;i++){
        int idx = i*256 + tid;   // < 1280
        int row = idx>>4, seg = idx&15;
        unsigned short v0,v1,v2,v3;
        if (row < 32){
            v0=lTc[row*64+seg*4+0]; v1=lTc[row*64+seg*4+1];
            v2=lTc[row*64+seg*4+2]; v3=lTc[row*64+seg*4+3];
        } else if (row < 64){
            int r = row-32;
            v0=lTs[r*64+seg*4+0]; v1=lTs[r*64+seg*4+1];
            v2=lTs[r*64+seg*4+2]; v3=lTs[r*64+seg*4+3];
        } else if (row == 64){
            v0=f2bf(lwv[seg*4+0]); v1=f2bf(lwv[seg*4+1]);
            v2=f2bf(lwv[seg*4+2]); v3=f2bf(lwv[seg*4+3]);
        } else { v0=v1=v2=v3=0; }
        uint2 u;
        u.x = (unsigned int)v0 | ((unsigned int)v1<<16);
        u.y = (unsigned int)v2 | ((unsigned int)v3<<16);
        *(uint2*)&wBt[((size_t)b*80+row)*NPAD + n0 + seg*4] = u;
    }
}

// ---------------- setup: fc0 ----------------

__global__ __launch_bounds__(256) void fc0_kernel(
    const float* __restrict__ x, const float* __restrict__ w,
    const float* __restrict__ bvec, unsigned short* __restrict__ hN,
    unsigned short* __restrict__ hT)
{
    int idx = blockIdx.x*256 + threadIdx.x;
    if (idx >= B_*N_) return;
    int b = idx / N_, n = idx - b*N_;
    float x0 = x[(size_t)idx*3+0], x1 = x[(size_t)idx*3+1], x2 = x[(size_t)idx*3+2];
    unsigned short* hr = hN + (size_t)idx*C_;
    for (int c=0;c<C_;c+=4){
        float4 v;
        v.x = bvec[c+0] + x0*w[(c+0)*3] + x1*w[(c+0)*3+1] + x2*w[(c+0)*3+2];
        v.y = bvec[c+1] + x0*w[(c+1)*3] + x1*w[(c+1)*3+1] + x2*w[(c+1)*3+2];
        v.z = bvec[c+2] + x0*w[(c+2)*3] + x1*w[(c+2)*3+1] + x2*w[(c+2)*3+2];
        v.w = bvec[c+3] + x0*w[(c+3)*3] + x1*w[(c+3)*3+1] + x2*w[(c+3)*3+2];
        uint2 u; u.x = pack2(v.x,v.y); u.y = pack2(v.z,v.w);
        *(uint2*)(hr+c) = u;
        hT[((size_t)b*C_+c+0)*NPAD + n] = f2bf(v.x);
        hT[((size_t)b*C_+c+1)*NPAD + n] = f2bf(v.y);
        hT[((size_t)b*C_+c+2)*NPAD + n] = f2bf(v.z);
        hT[((size_t)b*C_+c+3)*NPAD + n] = f2bf(v.w);
    }
}

// ---------------- CSR build ----------------

__global__ __launch_bounds__(256) void hist_kernel(
    const int* __restrict__ edges, int* __restrict__ cnt)
{
    int idx = blockIdx.x*256 + threadIdx.x;
    if (idx >= B_*E_) return;
    int b = idx / E_;
    int t = edges[(size_t)idx*2];
    atomicAdd(cnt + b*N_ + t, 1);
}

__global__ __launch_bounds__(1024) void scan_kernel(
    const int* __restrict__ cnt, int* __restrict__ rowptr, int* __restrict__ cur)
{
    __shared__ int wsum[16];
    int b = blockIdx.x, tid = threadIdx.x;
    int lane = tid & 63, wv = tid >> 6;
    const int CHUNK = 20;
    int start = tid * CHUNK;
    int lc[CHUNK];
    int lsum = 0;
    #pragma unroll
    for (int i=0;i<CHUNK;i++){
        int n = start + i;
        int v = (n < N_) ? cnt[b*N_+n] : 0;
        lc[i] = v; lsum += v;
    }
    int v = lsum;
    #pragma unroll
    for (int off=1; off<64; off<<=1){
        int t = __shfl_up(v, off, 64);
        if (lane >= off) v += t;
    }
    if (lane == 63) wsum[wv] = v;
    __syncthreads();
    if (wv == 0 && lane < 16){
        int wv2 = wsum[lane];
        #pragma unroll
        for (int off=1; off<16; off<<=1){
            int t = __shfl_up(wv2, off, 64);
            if (lane >= off) wv2 += t;
        }
        wsum[lane] = wv2;
    }
    __syncthreads();
    int waveoff = (wv == 0) ? 0 : wsum[wv-1];
    int excl = waveoff + v - lsum;
    #pragma unroll
    for (int i=0;i<CHUNK;i++){
        int n = start + i;
        if (n < N_){
            rowptr[b*(N_+1)+n] = excl;
            cur[b*N_+n] = excl;
            excl += lc[i];
        }
    }
    if (tid == 0) rowptr[b*(N_+1)+N_] = E_;
}

__global__ __launch_bounds__(256) void fill_kernel(
    const int* __restrict__ edges, int* __restrict__ cur, int* __restrict__ csre)
{
    int idx = blockIdx.x*256 + threadIdx.x;
    if (idx >= B_*E_) return;
    int b = idx / E_, e = idx - b*E_;
    int t = edges[(size_t)idx*2];
    int pos = atomicAdd(cur + b*N_ + t, 1);
    csre[(size_t)b*E_ + pos] = e;
}

// ---------------- per-layer: weight concat f32 -> bf16 (once per layer) ----------------
// wcat[o][0:128] = ww[o][:], wcat[o][128:512] = gw[o][:]

__global__ __launch_bounds__(256) void wconv_kernel(
    const float* __restrict__ ww_l, const float* __restrict__ gw_l,
    unsigned short* __restrict__ wcat)
{
    int o = blockIdx.x, t = threadIdx.x;
    int k = t*2;
    float a, bv;
    if (k < 128){ a = ww_l[(size_t)o*C_ + k];      bv = ww_l[(size_t)o*C_ + k + 1]; }
    else        { a = gw_l[(size_t)o*384 + k-128]; bv = gw_l[(size_t)o*384 + k-127]; }
    *(unsigned int*)&wcat[(size_t)o*512 + k] = pack2(a, bv);
}

// ---------------- per-layer: spectral reduce as MFMA GEMM ----------------

__global__ __launch_bounds__(256) void stageA_kernel(
    const unsigned short* __restrict__ hT, const unsigned short* __restrict__ wBt,
    float* __restrict__ part)
{
    __shared__ unsigned short As[80*72];   // [kcol][node], stride 72
    __shared__ unsigned short Bs[128*72];  // [c][node], stride 72
    int b = blockIdx.y, blk = blockIdx.x;
    int tid = threadIdx.x;
    int wv = tid>>6, lane = tid&63, l15 = lane&15, quad = lane>>4;
    floatx4 acc[5][2];
    #pragma unroll
    for (int mt=0;mt<5;mt++){ acc[mt][0]=(floatx4){0,0,0,0}; acc[mt][1]=(floatx4){0,0,0,0}; }
    size_t hbase = (size_t)b*C_*NPAD;
    size_t wbase = (size_t)b*80*NPAD;
    for (int cidx=0; cidx<5; ++cidx){
        int n0c = blk*320 + cidx*64;
        #pragma unroll
        for (int i=0;i<3;i++){
            int idx = i*256 + tid;
            if (idx < 640){
                int row = idx>>3, seg = idx&7;
                uint4 v = *(const uint4*)&wBt[wbase + (size_t)row*NPAD + n0c + seg*8];
                *(uint4*)&As[row*72 + seg*8] = v;
            }
        }
        #pragma unroll
        for (int i=0;i<4;i++){
            int idx = i*256 + tid;
            int row = idx>>3, seg = idx&7;
            int node = n0c + seg*8;
            uint4 v = make_uint4(0,0,0,0);
            if (node < N_)
                v = *(const uint4*)&hT[hbase + (size_t)row*NPAD + node];
            *(uint4*)&Bs[row*72 + seg*8] = v;
        }
        __syncthreads();
        #pragma unroll
        for (int ks=0; ks<2; ks++){
            short8 bfrag[2];
            #pragma unroll
            for (int ot=0;ot<2;ot++)
                bfrag[ot] = *(const short8*)&Bs[(wv*32+ot*16+l15)*72 + ks*32 + quad*8];
            #pragma unroll
            for (int mt=0;mt<5;mt++){
                short8 af = *(const short8*)&As[(mt*16+l15)*72 + ks*32 + quad*8];
                acc[mt][0] = __builtin_amdgcn_mfma_f32_16x16x32_bf16(af, bfrag[0], acc[mt][0], 0,0,0);
                acc[mt][1] = __builtin_amdgcn_mfma_f32_16x16x32_bf16(af, bfrag[1], acc[mt][1], 0,0,0);
            }
        }
        __syncthreads();
    }
    float* pblk = part + ((size_t)(b*64+blk))*80*C_;
    #pragma unroll
    for (int mt=0;mt<5;mt++){
        #pragma unroll
        for (int ot=0;ot<2;ot++){
            int c = wv*32 + ot*16 + l15;
            #pragma unroll
            for (int r=0;r<4;r++){
                int kcol = mt*16 + quad*4 + r;
                pblk[kcol*C_ + c] = acc[mt][ot][r];
            }
        }
    }
}

__global__ __launch_bounds__(256) void reducePart_kernel(
    const float* __restrict__ part, float* __restrict__ xq)
{
    int idx = blockIdx.x*256 + threadIdx.x;
    if (idx >= B_*80*C_) return;
    int b = idx / (80*C_);
    int r = idx - b*80*C_;
    float s = 0.f;
    for (int blk=0; blk<64; blk++)
        s += part[((size_t)(b*64+blk))*80*C_ + r];
    xq[idx] = s;
}

// ---------------- per-layer: mode mixing (tiny); wf emitted as bf16 ----------------

__global__ __launch_bounds__(64) void mix_kernel(
    const float* __restrict__ xq, const float* __restrict__ swc_l,
    const float* __restrict__ sws_l, const float* __restrict__ sw0_l,
    unsigned short* __restrict__ wfb, float* __restrict__ f0)
{
    __shared__ float s64[64];
    int o = blockIdx.x, b = blockIdx.y, t = threadIdx.x;
    int k = t & 31; bool isS = t >= 32;
    const float* xqb = xq + (size_t)b*80*C_;
    float acc = 0.f;
    for (int c=0;c<C_;c++){
        float xc = xqb[k*C_ + c], xs = xqb[(32+k)*C_ + c];
        float wc = swc_l[((size_t)c*C_+o)*K_ + k];
        float ws = sws_l[((size_t)c*C_+o)*K_ + k];
        acc += isS ? (xs*wc + xc*ws) : (xc*wc - xs*ws);
    }
    wfb[((size_t)b*C_+o)*64 + t] = f2bf(isS ? -2.f*acc : 2.f*acc);
    float p = xqb[64*C_ + t]      * sw0_l[(size_t)t*C_+o]
            + xqb[64*C_ + 64 + t] * sw0_l[(size_t)(t+64)*C_+o];
    s64[t] = p; __syncthreads();
    if (t==0){
        float s=0.f;
        for (int i=0;i<64;i++) s += s64[i];
        f0[b*C_+o] = s;
    }
}

// ---------------- per-layer: gradient gather (CSR), bf16 h rows ----------------

__global__ __launch_bounds__(256) void grad_kernel(
    const unsigned short* __restrict__ hN, const int* __restrict__ edges,
    const float* __restrict__ egw, const int* __restrict__ rowptr,
    const int* __restrict__ csre, unsigned short* __restrict__ g)
{
    int b = blockIdx.y;
    int n = blockIdx.x*4 + (threadIdx.x >> 6);
    int cp = threadIdx.x & 63;
    size_t bN = (size_t)b*N_;
    int r0 = rowptr[b*(N_+1)+n], r1 = rowptr[b*(N_+1)+n+1];
    unsigned int hcu = *(const unsigned int*)&hN[(bN+n)*C_ + cp*2];
    float hc0 = bf2f((unsigned short)hcu), hc1 = bf2f((unsigned short)(hcu>>16));
    float a00=0.f,a01=0.f,a02=0.f, a10=0.f,a11=0.f,a12=0.f;
    if (r0 < r1){
        int e = csre[(size_t)b*E_ + r0];
        size_t eb = (size_t)b*E_ + e;
        int src = edges[eb*2+1];
        float w0 = egw[eb*3+0], w1 = egw[eb*3+1], w2 = egw[eb*3+2];
        for (int i=r0; i<r1; i++){
            unsigned int su = *(const unsigned int*)&hN[(bN+src)*C_ + cp*2];
            int nsrc = 0; float nw0=0.f, nw1=0.f, nw2=0.f;
            if (i+1 < r1){
                int e2 = csre[(size_t)b*E_ + i+1];
                size_t eb2 = (size_t)b*E_ + e2;
                nsrc = edges[eb2*2+1];
                nw0 = egw[eb2*3+0]; nw1 = egw[eb2*3+1]; nw2 = egw[eb2*3+2];
            }
            float d0 = bf2f((unsigned short)su) - hc0;
            float d1 = bf2f((unsigned short)(su>>16)) - hc1;
            a00 += w0*d0; a01 += w1*d0; a02 += w2*d0;
            a10 += w0*d1; a11 += w1*d1; a12 += w2*d1;
            src = nsrc; w0 = nw0; w1 = nw1; w2 = nw2;
        }
    }
    unsigned short* gr = g + (bN+n)*(size_t)384 + cp*6;
    *(unsigned int*)(gr+0) = pack2(a00,a01);
    *(unsigned int*)(gr+2) = pack2(a02,a10);
    *(unsigned int*)(gr+4) = pack2(a11,a12);
}

// ---------------- per-layer: fused MFMA GEMM (K=576) + epilogue ----------------
// A staged in double-buffered LDS (1 barrier/chunk); W fragments loaded
// directly from global bf16 (wcat L2-resident, each fragment read by 1 wave).

__global__ __launch_bounds__(256) void gemm_kernel(
    const unsigned short* __restrict__ hN, const unsigned short* __restrict__ g,
    const unsigned short* __restrict__ bcb, const unsigned short* __restrict__ bsb,
    const unsigned short* __restrict__ wcat, const unsigned short* __restrict__ wfb,
    const float* __restrict__ wb_l, const float* __restrict__ gb_l,
    const float* __restrict__ f0,
    unsigned short* __restrict__ hNo, unsigned short* __restrict__ hT, int apply_gelu)
{
    __shared__ unsigned short As[2][64*72];
    int b = blockIdx.y;
    int nb0 = blockIdx.x*64;
    int tid = threadIdx.x;
    int a_n = tid>>2, a_s = tid&3;
    int wv = tid>>6, lane = tid&63, l15 = lane&15, quad = lane>>4;
    floatx4 acc[4][2];
    #pragma unroll
    for (int mt=0;mt<4;mt++)
        #pragma unroll
        for (int ot=0;ot<2;ot++) acc[mt][ot] = (floatx4){0.f,0.f,0.f,0.f};
    size_t bN = (size_t)b*N_;
    int gn = nb0 + a_n; bool av = gn < N_;
    size_t row = bN + (size_t)(av ? gn : 0);
    const unsigned short* hrow  = hN + row*C_;
    const unsigned short* grow  = g  + row*384;
    const unsigned short* bcrow = bcb + row*K_;
    const unsigned short* bsrow = bsb + row*K_;
    int o0 = wv*32 + l15, o1 = o0 + 16;
    const unsigned short* w0p = wcat + (size_t)o0*512 + quad*8;
    const unsigned short* w1p = wcat + (size_t)o1*512 + quad*8;
    const unsigned short* fb0 = wfb + ((size_t)b*C_ + o0)*64 + quad*8;
    const unsigned short* fb1 = wfb + ((size_t)b*C_ + o1)*64 + quad*8;

    auto loadA = [&](int ch, uint4& v0, uint4& v1){
        v0 = make_uint4(0,0,0,0); v1 = make_uint4(0,0,0,0);
        if (av){
            if (ch < 8){
                const uint4* p = (ch<2) ? (const uint4*)(hrow + ch*64 + a_s*16)
                                        : (const uint4*)(grow + (ch-2)*64 + a_s*16);
                v0 = p[0]; v1 = p[1];
            } else {
                const uint4* p = (a_s < 2) ? (const uint4*)(bcrow + a_s*16)
                                           : (const uint4*)(bsrow + (a_s-2)*16);
                v0 = p[0]; v1 = p[1];
            }
        }
    };

    uint4 c0, c1;
    loadA(0, c0, c1);
    *(uint4*)&As[0][a_n*72 + a_s*16]     = c0;
    *(uint4*)&As[0][a_n*72 + a_s*16 + 8] = c1;
    int p = 0;
    for (int ch=0; ch<9; ++ch){
        uint4 n0v, n1v;
        if (ch < 8) loadA(ch+1, n0v, n1v);
        __syncthreads();
        #pragma unroll
        for (int ks=0; ks<2; ks++){
            short8 bfr0, bfr1;
            if (ch < 8){
                bfr0 = *(const short8*)(w0p + ch*64 + ks*32);
                bfr1 = *(const short8*)(w1p + ch*64 + ks*32);
            } else {
                bfr0 = *(const short8*)(fb0 + ks*32);
                bfr1 = *(const short8*)(fb1 + ks*32);
            }
            #pragma unroll
            for (int mt=0; mt<4; mt++){
                short8 af = *(const short8*)&As[p][(mt*16+l15)*72 + ks*32 + quad*8];
                acc[mt][0] = __builtin_amdgcn_mfma_f32_16x16x32_bf16(af, bfr0, acc[mt][0], 0,0,0);
                acc[mt][1] = __builtin_amdgcn_mfma_f32_16x16x32_bf16(af, bfr1, acc[mt][1], 0,0,0);
            }
        }
        if (ch < 8){
            *(uint4*)&As[1-p][a_n*72 + a_s*16]     = n0v;
            *(uint4*)&As[1-p][a_n*72 + a_s*16 + 8] = n1v;
            p ^= 1;
        }
    }
    float biasv[2]; int oo[2];
    oo[0]=o0; oo[1]=o1;
    #pragma unroll
    for (int ot=0;ot<2;ot++)
        biasv[ot] = wb_l[oo[ot]] + gb_l[oo[ot]] + f0[(size_t)b*C_ + oo[ot]];
    unsigned short* AsF = &As[0][0];   // reuse as [o][n] 128x72
    if (apply_gelu) __syncthreads();   // ensure all LDS reads of main loop done
    #pragma unroll
    for (int mt=0;mt<4;mt++){
        #pragma unroll
        for (int ot=0;ot<2;ot++){
            int nb = nb0 + mt*16 + quad*4;
            float v4[4];
            #pragma unroll
            for (int r=0;r<4;r++){
                float vv = acc[mt][ot][r] + biasv[ot];
                if (apply_gelu) vv = gelu_exact(vv);
                v4[r] = vv;
                if (nb + r < N_) hNo[(bN+nb+r)*C_ + oo[ot]] = f2bf(vv);
            }
            if (apply_gelu){
                uint2 u; u.x = pack2(v4[0],v4[1]); u.y = pack2(v4[2],v4[3]);
                *(uint2*)&AsF[oo[ot]*72 + mt*16 + quad*4] = u;
            }
        }
    }
    if (apply_gelu){
        __syncthreads();
        int orow = tid>>1, half = tid&1;
        uint4 u0 = *(const uint4*)&AsF[orow*72 + half*32];
        uint4 u1 = *(const uint4*)&AsF[orow*72 + half*32 + 8];
        unsigned short* dst = &hT[((size_t)b*C_ + orow)*NPAD + nb0 + half*32];
        *(uint4*)dst       = u0;
        *(uint4*)(dst + 8) = u1;
    }
}

// ---------------- head: fc1 + gelu + fc2 (bf16 h input) ----------------

__global__ __launch_bounds__(256) void final_kernel(
    const unsigned short* __restrict__ hN,
    const float* __restrict__ fc1w, const float* __restrict__ fc1b,
    const float* __restrict__ fc2w, const float* __restrict__ fc2b,
    float* __restrict__ out)
{
    __shared__ float As[64*68];
    __shared__ float Ws[64*132];
    __shared__ float p2[256];
    int b = blockIdx.y;
    int nb0 = blockIdx.x*64;
    int tid = threadIdx.x;
    int a_n = tid>>2, a_q = tid&3;
    int w_o = tid>>1, w_h = tid&1;
    int o_base = (tid&31)*4, n_base = (tid>>5)*8;
    float acc[8][4];
    #pragma unroll
    for (int j=0;j<8;j++)
        #pragma unroll
        for (int i=0;i<4;i++) acc[j][i]=0.f;
    size_t bN = (size_t)b*N_;
    int gn = nb0 + a_n; bool av = gn < N_;
    size_t row = bN + (size_t)(av ? gn : 0);
    const unsigned short* hrow = hN + row*C_;
    for (int ch=0; ch<2; ++ch){
        #pragma unroll
        for (int i=0;i<2;i++){
            int kl = a_q*16 + i*8;
            uint4 u = make_uint4(0,0,0,0);
            if (av) u = *(const uint4*)(hrow + ch*64 + kl);
            As[(kl+0)*68 + a_n] = bf2f((unsigned short)u.x);
            As[(kl+1)*68 + a_n] = bf2f((unsigned short)(u.x>>16));
            As[(kl+2)*68 + a_n] = bf2f((unsigned short)u.y);
            As[(kl+3)*68 + a_n] = bf2f((unsigned short)(u.y>>16));
            As[(kl+4)*68 + a_n] = bf2f((unsigned short)u.z);
            As[(kl+5)*68 + a_n] = bf2f((unsigned short)(u.z>>16));
            As[(kl+6)*68 + a_n] = bf2f((unsigned short)u.w);
            As[(kl+7)*68 + a_n] = bf2f((unsigned short)(u.w>>16));
        }
        #pragma unroll
        for (int i=0;i<8;i++){
            int kl = w_h*32 + i*4;
            const float* wp = fc1w + (size_t)w_o*C_ + ch*64 + kl;
            float4 v = *(const float4*)wp;
            Ws[(kl+0)*132 + w_o] = v.x;
            Ws[(kl+1)*132 + w_o] = v.y;
            Ws[(kl+2)*132 + w_o] = v.z;
            Ws[(kl+3)*132 + w_o] = v.w;
        }
        __syncthreads();
        #pragma unroll 4
        for (int kk=0;kk<64;kk++){
            float4 wv = *(const float4*)&Ws[kk*132 + o_base];
            float4 a0 = *(const float4*)&As[kk*68 + n_base];
            float4 a1 = *(const float4*)&As[kk*68 + n_base + 4];
            float avj[8] = {a0.x,a0.y,a0.z,a0.w,a1.x,a1.y,a1.z,a1.w};
            float wvi[4] = {wv.x,wv.y,wv.z,wv.w};
            #pragma unroll
            for (int j=0;j<8;j++)
                #pragma unroll
                for (int i=0;i<4;i++)
                    acc[j][i] += avj[j]*wvi[i];
        }
        __syncthreads();
    }
    #pragma unroll
    for (int j=0;j<8;j++){
        int n_l = n_base + j;
        float4 v;
        v.x = gelu_exact(acc[j][0] + fc1b[o_base+0]);
        v.y = gelu_exact(acc[j][1] + fc1b[o_base+1]);
        v.z = gelu_exact(acc[j][2] + fc1b[o_base+2]);
        v.w = gelu_exact(acc[j][3] + fc1b[o_base+3]);
        *(float4*)&Ws[n_l*132 + o_base] = v;
    }
    __syncthreads();
    int n_l = tid & 63, fq = tid >> 6;
    float p = 0.f;
    for (int f = fq*32; f < fq*32+32; f++)
        p += fc2w[f] * Ws[n_l*132 + f];
    p2[tid] = p; __syncthreads();
    if (tid < 64){
        float s = p2[tid] + p2[tid+64] + p2[tid+128] + p2[tid+192] + fc2b[0];
        int n = nb0 + tid;
        if (n < N_) out[bN + n] = s;
    }
}

// ---------------- launch ----------------

extern "C" void kernel_launch(void* const* d_in, const int* in_sizes, int n_in,
                              void* d_out, int out_size, void* d_ws, size_t ws_size,
                              hipStream_t stream)
{
    const float* x      = (const float*)d_in[0];
    const float* nodes  = (const float*)d_in[2];
    const float* nw     = (const float*)d_in[3];
    const int*   edges  = (const int*)  d_in[4];
    const float* egw    = (const float*)d_in[5];
    const float* modes  = (const float*)d_in[6];
    const float* latent = (const float*)d_in[7];
    const float* fc0w   = (const float*)d_in[8];
    const float* fc0b   = (const float*)d_in[9];
    const float* swc    = (const float*)d_in[10];
    const float* sws    = (const float*)d_in[11];
    const float* sw0    = (const float*)d_in[12];
    const float* ww     = (const float*)d_in[13];
    const float* wb     = (const float*)d_in[14];
    const float* gw     = (const float*)d_in[15];
    const float* gb     = (const float*)d_in[16];
    const float* fc1w   = (const float*)d_in[17];
    const float* fc1b   = (const float*)d_in[18];
    const float* fc2w   = (const float*)d_in[19];
    const float* fc2b   = (const float*)d_in[20];
    float* out = (float*)d_out;

    char* W = (char*)d_ws;
    size_t off = 0;
    unsigned short* bcB = (unsigned short*)(W+off); off += (size_t)B_*N_*K_*2;
    unsigned short* bsB = (unsigned short*)(W+off); off += (size_t)B_*N_*K_*2;
    unsigned short* wBt = (unsigned short*)(W+off); off += (size_t)B_*80*NPAD*2;
    unsigned short* hT  = (unsigned short*)(W+off); off += (size_t)B_*C_*NPAD*2;
    unsigned short* hNa = (unsigned short*)(W+off); off += (size_t)B_*N_*C_*2;
    unsigned short* hNb = (unsigned short*)(W+off); off += (size_t)B_*N_*C_*2;
    unsigned short* g   = (unsigned short*)(W+off); off += (size_t)B_*N_*C_*3*2;
    unsigned short* wcat= (unsigned short*)(W+off); off += (size_t)C_*512*2;
    unsigned short* wfb = (unsigned short*)(W+off); off += (size_t)B_*C_*64*2;
    float* part = (float*)(W+off); off += (size_t)B_*64*80*C_*4;
    float* xq   = (float*)(W+off); off += (size_t)B_*80*C_*4;
    float* f0   = (float*)(W+off); off += (size_t)B_*C_*4;
    int* cnt    = (int*)(W+off); off += (size_t)B_*N_*4;
    int* rowptr = (int*)(W+off); off += (size_t)B_*(N_+1)*4 + 16;
    int* cur    = (int*)(W+off); off += (size_t)B_*N_*4;
    int* csre   = (int*)(W+off);

    hipMemsetAsync(cnt, 0, (size_t)B_*N_*sizeof(int), stream);
    basis_kernel<<<dim3(NPAD/64, B_), 256, 0, stream>>>(
        nodes, nw, modes, latent, bcB, bsB, wBt);
    fc0_kernel  <<<(B_*N_+255)/256, 256, 0, stream>>>(x, fc0w, fc0b, hNa, hT);
    hist_kernel <<<(B_*E_+255)/256, 256, 0, stream>>>(edges, cnt);
    scan_kernel <<<B_, 1024, 0, stream>>>(cnt, rowptr, cur);
    fill_kernel <<<(B_*E_+255)/256, 256, 0, stream>>>(edges, cur, csre);

    unsigned short* hc = hNa; unsigned short* hn = hNb;
    for (int l=0; l<3; ++l){
        wconv_kernel<<<C_, 256, 0, stream>>>(
            ww + (size_t)l*C_*C_, gw + (size_t)l*C_*C_*3, wcat);
        stageA_kernel<<<dim3(64,B_), 256, 0, stream>>>(hT, wBt, part);
        reducePart_kernel<<<(B_*80*C_+255)/256, 256, 0, stream>>>(part, xq);
        mix_kernel<<<dim3(C_,B_), 64, 0, stream>>>(
            xq, swc + (size_t)l*C_*C_*K_, sws + (size_t)l*C_*C_*K_,
            sw0 + (size_t)l*C_*C_, wfb, f0);
        grad_kernel<<<dim3(N_/4,B_), 256, 0, stream>>>(hc, edges, egw, rowptr, csre, g);
        gemm_kernel<<<dim3((N_+63)/64,B_), 256, 0, stream>>>(
            hc, g, bcB, bsB, wcat, wfb,
            wb + (size_t)l*C_, gb + (size_t)l*C_,
            f0, hn, hT, (l<2) ? 1 : 0);
        unsigned short* t = hc; hc = hn; hn = t;
    }
    final_kernel<<<dim3((N_+63)/64,B_), 256, 0, stream>>>(hc, fc1w, fc1b, fc2w, fc2b, out);
}